// Round 8
// baseline (560.236 us; speedup 1.0000x reference)
//
#include <hip/hip_runtime.h>
#include <hip/hip_bf16.h>
#include <math.h>

#define M_TOK 2048
#define DDIM  1024
#define FDIM  4096
#define NEXP  8
#define TOTROWS 5120
#define NTMAX 40

typedef __attribute__((ext_vector_type(8))) short short8;
typedef __attribute__((ext_vector_type(4))) short short4v;
typedef __attribute__((ext_vector_type(4))) float f32x4;
typedef unsigned short ushort_t;

// ---------- helpers ----------
__device__ inline unsigned short f2b(float f) {        // f32 -> bf16 RNE
  unsigned int u = __float_as_uint(f);
  u = u + 0x7FFFu + ((u >> 16) & 1u);
  return (unsigned short)(u >> 16);
}

__device__ inline float gelu_tanh(float u) {           // jax.nn.gelu approximate=True
  float u3 = u * u * u;
  float a  = 0.7978845608028654f * (u + 0.044715f * u3);
  float e  = __expf(2.0f * a);
  float t  = 1.0f - 2.0f / (e + 1.0f);                 // tanh(a), inf-safe
  return 0.5f * u * (1.0f + t);
}

__device__ inline void gload_lds16(const void* g, void* l) {
  __builtin_amdgcn_global_load_lds(
      (const __attribute__((address_space(1))) unsigned int*)g,
      (__attribute__((address_space(3))) unsigned int*)l, 16, 0, 0);
}

__device__ inline float fget(const float4& v, int j) {
  return j == 0 ? v.x : j == 1 ? v.y : j == 2 ? v.z : v.w;
}

// ---------- 1: router ----------
__global__ void router_kernel(const float* __restrict__ x, const float* __restrict__ rw,
                              int* __restrict__ cnt, int* __restrict__ tmp_tok,
                              float* __restrict__ tmp_gate) {
  int tok  = blockIdx.x * 4 + (threadIdx.x >> 6);
  int lane = threadIdx.x & 63;
  const float* xr = x + (size_t)tok * DDIM;
  double acc[NEXP];
#pragma unroll
  for (int e = 0; e < NEXP; e++) acc[e] = 0.0;
  for (int d = lane; d < DDIM; d += 64) {
    double xv = (double)xr[d];
    const float* rp = rw + (size_t)d * NEXP;
#pragma unroll
    for (int e = 0; e < NEXP; e++) acc[e] += xv * (double)rp[e];
  }
#pragma unroll
  for (int off = 32; off >= 1; off >>= 1) {
#pragma unroll
    for (int e = 0; e < NEXP; e++) acc[e] += __shfl_down(acc[e], off, 64);
  }
  if (lane == 0) {
    double mx = acc[0];
    for (int e = 1; e < NEXP; e++) mx = fmax(mx, acc[e]);
    double p[NEXP], sum = 0.0;
    for (int e = 0; e < NEXP; e++) { p[e] = exp(acc[e] - mx); sum += p[e]; }
    for (int e = 0; e < NEXP; e++) p[e] /= sum;
    int i0 = 0;
    for (int e = 1; e < NEXP; e++) if (p[e] > p[i0]) i0 = e;
    int i1 = (i0 == 0) ? 1 : 0;
    for (int e = 0; e < NEXP; e++) if (e != i0 && p[e] > p[i1]) i1 = e;
    int pos0 = atomicAdd(&cnt[i0], 1);
    tmp_tok[i0 * M_TOK + pos0]  = tok;
    tmp_gate[i0 * M_TOK + pos0] = (float)p[i0];
    int pos1 = atomicAdd(&cnt[i1], 1);
    tmp_tok[i1 * M_TOK + pos1]  = tok;
    tmp_gate[i1 * M_TOK + pos1] = (float)p[i1];
  }
}

// ---------- 2: offsets (pad to 128), tile list, compact ----------
__global__ void finalize_kernel(const int* __restrict__ cnt, int* __restrict__ pofs,
                                int* __restrict__ meta, int* __restrict__ tle,
                                int* __restrict__ tlr, int* __restrict__ ptok,
                                float* __restrict__ pgate, const int* __restrict__ tmp_tok,
                                const float* __restrict__ tmp_gate) {
  __shared__ int ofs[NEXP];
  if (threadIdx.x == 0) {
    int o = 0, t = 0;
    for (int e = 0; e < NEXP; e++) {
      ofs[e] = o; pofs[e] = o;
      int nt = (cnt[e] + 127) >> 7;
      for (int i = 0; i < nt; i++) { tle[t] = e; tlr[t] = o + i * 128; t++; }
      o += nt << 7;
    }
    meta[0] = o; meta[1] = t;
  }
  __syncthreads();
  for (int i = threadIdx.x; i < NEXP * M_TOK; i += 256) {
    int e = i >> 11, sl = i & 2047;
    int c = cnt[e];
    int padded = ((c + 127) >> 7) << 7;
    if (sl < padded) {
      int dst = ofs[e] + sl;
      if (sl < c) { ptok[dst] = tmp_tok[i]; pgate[dst] = tmp_gate[i]; }
      else        { ptok[dst] = -1;         pgate[dst] = 0.0f; }
    }
  }
}

// ---------- 3: gather x rows -> bf16 Xg ----------
__global__ void gather_kernel(const float* __restrict__ x, const int* __restrict__ ptok,
                              const int* __restrict__ meta, ushort_t* __restrict__ Xg) {
  int r = blockIdx.x;
  if (r >= meta[0]) return;
  int tok = ptok[r];
  int t = threadIdx.x;
  ushort4 b;
  if (tok >= 0) {
    float4 v = *(const float4*)(x + (size_t)tok * DDIM + t * 4);
    b.x = f2b(v.x); b.y = f2b(v.y); b.z = f2b(v.z); b.w = f2b(v.w);
  } else {
    b.x = 0; b.y = 0; b.z = 0; b.w = 0;
  }
  *(ushort4*)(Xg + (size_t)r * DDIM + t * 4) = b;
}

// ---------- 3b: convert+transpose+fold-scale (round-6 measured version) ----------
__global__ void convert_kernel(const float* __restrict__ wv, const float* __restrict__ sv,
                               const float* __restrict__ w,  const float* __restrict__ s,
                               const float* __restrict__ w1, const float* __restrict__ s1,
                               ushort_t* __restrict__ WvT, ushort_t* __restrict__ WT,
                               ushort_t* __restrict__ W1T) {
  int z = blockIdx.z;
  const float* src   = z == 0 ? wv : z == 1 ? w : w1;
  const float* scale = z == 0 ? sv : z == 1 ? s : s1;
  ushort_t* dst      = z == 0 ? WvT : z == 1 ? WT : W1T;
  int K = z == 2 ? FDIM : DDIM;
  int N = z == 2 ? DDIM : FDIM;

  int e = blockIdx.y;
  int ntn = N >> 7;
  int tk = blockIdx.x / ntn;
  int tn = blockIdx.x - tk * ntn;
  int k0 = tk * 128, n0 = tn * 128;

  const float* S  = src + (size_t)e * K * N + (size_t)k0 * N + n0;
  ushort_t*   D   = dst + (size_t)e * N * K + (size_t)n0 * K + k0;
  const float* sc = scale + (size_t)e * N + n0;

  __shared__ ushort_t lds[128][130];
  unsigned int* L = (unsigned int*)&lds[0][0];

  int t  = threadIdx.x;
  int lg = t >> 4;
  int ll = t & 15;

#pragma unroll
  for (int h = 0; h < 2; h++) {
    int c0 = h * 64 + ll * 4;
    float4 scv = *(const float4*)(sc + c0);
#pragma unroll
    for (int p = 0; p < 4; p++) {
      int r = p * 32 + lg * 2;
      float4 v0 = *(const float4*)(S + (size_t)r * N + c0);
      float4 v1 = *(const float4*)(S + (size_t)(r + 1) * N + c0);
#pragma unroll
      for (int j = 0; j < 4; j++) {
        unsigned int pk = (unsigned int)f2b(fget(v0, j) * fget(scv, j))
                        | ((unsigned int)f2b(fget(v1, j) * fget(scv, j)) << 16);
        L[(c0 + j) * 65 + (r >> 1)] = pk;
      }
    }
  }
  __syncthreads();

#pragma unroll
  for (int q = 0; q < 8; q++) {
    int n  = q * 16 + lg;
    int kc = ll * 8;
    int base = n * 65 + (kc >> 1);
    uint4 o;
    o.x = L[base + 0];
    o.y = L[base + 1];
    o.z = L[base + 2];
    o.w = L[base + 3];
    *(uint4*)(D + (size_t)n * K + kc) = o;
  }
}

// ---------- 4: GEMM1 — A via LDS (dbuf), B direct global->reg ----------
__launch_bounds__(256, 2)
__global__ void gemm1_kernel(const ushort_t* __restrict__ Xg,
                             const ushort_t* __restrict__ WvT, const ushort_t* __restrict__ WT,
                             const int* __restrict__ tle, const int* __restrict__ tlr,
                             const int* __restrict__ meta, ushort_t* __restrict__ G) {
  int b = blockIdx.x;                              // 1280 = 8*160
  int bid = (b & 7) * 160 + (b >> 3);              // bijective XCD chunk swizzle
  int ct = bid / NTMAX;
  int t  = bid - ct * NTMAX;
  if (t >= meta[1]) return;
  int e = tle[t], gr0 = tlr[t];

  __shared__ ushort_t As0[128][32], As1[128][32];  // 16 KB total

  int tid = threadIdx.x, wid = tid >> 6, lane = tid & 63;
  int wr = wid >> 1, wc = wid & 1;
  int srow = wid * 32 + (lane >> 2);
  int scol = (lane & 3) * 8;

  const ushort_t* Ap = Xg + (size_t)(gr0 + srow) * DDIM + scol;
  // B direct: lane-private fragment base.  col = ct*128 + wc*64 + ni*16 + (lane&15)
  const ushort_t* BvG = WvT + ((size_t)e * FDIM + ct * 128 + wc * 64 + (lane & 15)) * DDIM + (lane >> 4) * 8;
  const ushort_t* BwG = WT  + ((size_t)e * FDIM + ct * 128 + wc * 64 + (lane & 15)) * DDIM + (lane >> 4) * 8;

  f32x4 accv[4][4], accy[4][4];
  f32x4 zf = {0.f, 0.f, 0.f, 0.f};
#pragma unroll
  for (int mi = 0; mi < 4; mi++)
#pragma unroll
    for (int ni = 0; ni < 4; ni++) { accv[mi][ni] = zf; accy[mi][ni] = zf; }

  short8 af[4], bvf[4], bwf[4];

#define STGA1(As_, kk) do {                                                      \
    gload_lds16(Ap + (kk) * 32,             &As_[wid * 32][0]);                  \
    gload_lds16(Ap + (kk) * 32 + 16 * DDIM, &As_[wid * 32 + 16][0]);             \
  } while (0)

#define LDB1(kk) do {                                                            \
    _Pragma("unroll") for (int ni = 0; ni < 4; ni++) {                           \
      bvf[ni] = *(const short8*)(BvG + ((size_t)ni * 16) * DDIM + (kk) * 32);    \
      bwf[ni] = *(const short8*)(BwG + ((size_t)ni * 16) * DDIM + (kk) * 32); }  \
  } while (0)

#define RDA1(As_) do {                                                           \
    _Pragma("unroll") for (int mi = 0; mi < 4; mi++)                             \
      af[mi] = *(const short8*)&As_[wr*64 + mi*16 + (lane&15)][(lane>>4)*8];     \
  } while (0)

#define MM1() do {                                                               \
    _Pragma("unroll") for (int mi = 0; mi < 4; mi++)                             \
      _Pragma("unroll") for (int ni = 0; ni < 4; ni++) {                         \
        accv[mi][ni] = __builtin_amdgcn_mfma_f32_16x16x32_bf16(af[mi], bvf[ni], accv[mi][ni], 0, 0, 0); \
        accy[mi][ni] = __builtin_amdgcn_mfma_f32_16x16x32_bf16(af[mi], bwf[ni], accy[mi][ni], 0, 0, 0); } \
  } while (0)

  // prologue: A(0) oldest, then B(0)
  STGA1(As0, 0);
  __builtin_amdgcn_sched_barrier(0);
  LDB1(0);

  for (int kt = 0; kt < 32; kt += 2) {
    // ---- even tile: buf0 ----
    asm volatile("s_waitcnt vmcnt(8)" ::: "memory");   // A(kt) done; 8 B(kt) younger
    __builtin_amdgcn_sched_barrier(0);
    __builtin_amdgcn_s_barrier();
    if (kt + 1 < 32) { STGA1(As1, kt + 1); }           // A(kt+1) -> buf1
    __builtin_amdgcn_sched_barrier(0);
    RDA1(As0);
    MM1();                                             // compiler waits B(kt) regs + lgkm
    if (kt + 1 < 32) { LDB1(kt + 1); }                 // B(kt+1), WAR-safe after MFMA
    // ---- odd tile: buf1 ----
    asm volatile("s_waitcnt vmcnt(8)" ::: "memory");
    __builtin_amdgcn_sched_barrier(0);
    __builtin_amdgcn_s_barrier();
    if (kt + 2 < 32) { STGA1(As0, kt + 2); }
    __builtin_amdgcn_sched_barrier(0);
    RDA1(As1);
    MM1();
    if (kt + 2 < 32) { LDB1(kt + 2); }
  }
#undef STGA1
#undef LDB1
#undef RDA1
#undef MM1

#pragma unroll
  for (int ni = 0; ni < 4; ni++) {
    int coll = wc * 64 + ni * 16 + (lane & 15);
#pragma unroll
    for (int mi = 0; mi < 4; mi++)
#pragma unroll
      for (int q = 0; q < 4; q++) {
        int rowl = wr * 64 + mi * 16 + (lane >> 4) * 4 + q;
        float g = accv[mi][ni][q] * gelu_tanh(accy[mi][ni][q]);
        G[(size_t)(gr0 + rowl) * FDIM + ct * 128 + coll] = f2b(g);
      }
  }
}

// ---------- 5: GEMM2, K-split x4 — A via LDS (dbuf), B direct global->reg ----------
__launch_bounds__(256, 3)
__global__ void gemm2_kernel(const ushort_t* __restrict__ G,
                             const ushort_t* __restrict__ W1T,
                             const int* __restrict__ tle, const int* __restrict__ tlr,
                             const int* __restrict__ meta, const int* __restrict__ ptok,
                             const float* __restrict__ pgate, float* __restrict__ out) {
  int b = blockIdx.x;                              // 1280 = 8*160
  int bid = (b & 7) * 160 + (b >> 3);
  int grp = bid / NTMAX;                           // 0..31 = ct*4+ks
  int t = bid - grp * NTMAX;
  if (t >= meta[1]) return;
  int ct = grp >> 2, ks = grp & 3;
  int e = tle[t], gr0 = tlr[t];
  int k0 = ks * (FDIM / 4);

  __shared__ ushort_t As0[128][32], As1[128][32];

  int tid = threadIdx.x, wid = tid >> 6, lane = tid & 63;
  int wr = wid >> 1, wc = wid & 1;
  int srow = wid * 32 + (lane >> 2);
  int scol = (lane & 3) * 8;

  const ushort_t* Ap = G + (size_t)(gr0 + srow) * FDIM + k0 + scol;
  const ushort_t* BG = W1T + ((size_t)e * DDIM + ct * 128 + wc * 64 + (lane & 15)) * FDIM + k0 + (lane >> 4) * 8;

  f32x4 acc[4][4];
  f32x4 zf = {0.f, 0.f, 0.f, 0.f};
#pragma unroll
  for (int mi = 0; mi < 4; mi++)
#pragma unroll
    for (int ni = 0; ni < 4; ni++) acc[mi][ni] = zf;

  short8 af[4], bf[4];

#define STGA2(As_, kk) do {                                                      \
    gload_lds16(Ap + (kk) * 32,             &As_[wid * 32][0]);                  \
    gload_lds16(Ap + (kk) * 32 + 16 * FDIM, &As_[wid * 32 + 16][0]);             \
  } while (0)

#define LDB2(kk) do {                                                            \
    _Pragma("unroll") for (int ni = 0; ni < 4; ni++)                             \
      bf[ni] = *(const short8*)(BG + ((size_t)ni * 16) * FDIM + (kk) * 32);      \
  } while (0)

#define RDA2(As_) do {                                                           \
    _Pragma("unroll") for (int mi = 0; mi < 4; mi++)                             \
      af[mi] = *(const short8*)&As_[wr*64 + mi*16 + (lane&15)][(lane>>4)*8];     \
  } while (0)

#define MM2() do {                                                               \
    _Pragma("unroll") for (int mi = 0; mi < 4; mi++)                             \
      _Pragma("unroll") for (int ni = 0; ni < 4; ni++)                           \
        acc[mi][ni] = __builtin_amdgcn_mfma_f32_16x16x32_bf16(af[mi], bf[ni], acc[mi][ni], 0, 0, 0); \
  } while (0)

  STGA2(As0, 0);
  __builtin_amdgcn_sched_barrier(0);
  LDB2(0);

  for (int kt = 0; kt < 32; kt += 2) {
    asm volatile("s_waitcnt vmcnt(4)" ::: "memory");   // A(kt) done; 4 B(kt) younger
    __builtin_amdgcn_sched_barrier(0);
    __builtin_amdgcn_s_barrier();
    if (kt + 1 < 32) { STGA2(As1, kt + 1); }
    __builtin_amdgcn_sched_barrier(0);
    RDA2(As0);
    MM2();
    if (kt + 1 < 32) { LDB2(kt + 1); }
    asm volatile("s_waitcnt vmcnt(4)" ::: "memory");
    __builtin_amdgcn_sched_barrier(0);
    __builtin_amdgcn_s_barrier();
    if (kt + 2 < 32) { STGA2(As0, kt + 2); }
    __builtin_amdgcn_sched_barrier(0);
    RDA2(As1);
    MM2();
    if (kt + 2 < 32) { LDB2(kt + 2); }
  }
#undef STGA2
#undef LDB2
#undef RDA2
#undef MM2

#pragma unroll
  for (int ni = 0; ni < 4; ni++) {
    int coll = wc * 64 + ni * 16 + (lane & 15);
#pragma unroll
    for (int mi = 0; mi < 4; mi++)
#pragma unroll
      for (int q = 0; q < 4; q++) {
        int rowl = wr * 64 + mi * 16 + (lane >> 4) * 4 + q;
        int grow = gr0 + rowl;
        int tok  = ptok[grow];
        if (tok >= 0) {
          float val = acc[mi][ni][q] * pgate[grow];
          atomicAdd(out + (size_t)tok * DDIM + ct * 128 + coll, val);
        }
      }
  }
}

// ---------- launch ----------
extern "C" void kernel_launch(void* const* d_in, const int* in_sizes, int n_in,
                              void* d_out, int out_size, void* d_ws, size_t ws_size,
                              hipStream_t stream) {
  const float* x  = (const float*)d_in[0];
  const float* rw = (const float*)d_in[1];
  const float* wv = (const float*)d_in[2];
  const float* sv = (const float*)d_in[3];
  const float* w  = (const float*)d_in[4];
  const float* s  = (const float*)d_in[5];
  const float* w1 = (const float*)d_in[6];
  const float* s1 = (const float*)d_in[7];
  float* out = (float*)d_out;

  char* ws = (char*)d_ws;
  int*   cnt      = (int*)(ws + 0);
  int*   pofs     = (int*)(ws + 64);
  int*   meta     = (int*)(ws + 128);
  int*   tle      = (int*)(ws + 192);
  int*   tlr      = (int*)(ws + 512);
  int*   tmp_tok  = (int*)(ws + 1024);
  float* tmp_gate = (float*)(ws + 66560);
  int*   ptok     = (int*)(ws + 132096);
  float* pgate    = (float*)(ws + 152576);
  ushort_t* Xg    = (ushort_t*)(ws + 173056);      // 10 MB
  ushort_t* G     = (ushort_t*)(ws + 10658816);    // 40 MB
  ushort_t* WvT   = (ushort_t*)(ws + 52601856);    // 64 MB
  ushort_t* WT    = (ushort_t*)(ws + 119710720);   // 64 MB
  ushort_t* W1T   = (ushort_t*)(ws + 186819584);   // 64 MB (end ~242 MB)

  hipMemsetAsync(out, 0, (size_t)out_size * sizeof(float), stream);
  hipMemsetAsync(cnt, 0, NEXP * sizeof(int), stream);
  router_kernel<<<512, 256, 0, stream>>>(x, rw, cnt, tmp_tok, tmp_gate);
  finalize_kernel<<<1, 256, 0, stream>>>(cnt, pofs, meta, tle, tlr, ptok, pgate, tmp_tok, tmp_gate);
  gather_kernel<<<5120, 256, 0, stream>>>(x, ptok, meta, Xg);
  convert_kernel<<<dim3(256, 8, 3), 256, 0, stream>>>(wv, sv, w, s, w1, s1, WvT, WT, W1T);
  gemm1_kernel<<<1280, 256, 0, stream>>>(Xg, WvT, WT, tle, tlr, meta, G);
  gemm2_kernel<<<1280, 256, 0, stream>>>(G, W1T, tle, tlr, meta, ptok, pgate, out);
}

// Round 9
// 559.762 us; speedup vs baseline: 1.0008x; 1.0008x over previous
//
#include <hip/hip_runtime.h>
#include <hip/hip_bf16.h>
#include <math.h>

#define M_TOK 2048
#define DDIM  1024
#define FDIM  4096
#define NEXP  8
#define TOTROWS 5120
#define NTMAX 40

typedef __attribute__((ext_vector_type(8))) short short8;
typedef __attribute__((ext_vector_type(4))) float f32x4;
typedef unsigned short ushort_t;

// ---------- helpers ----------
__device__ inline unsigned short f2b(float f) {        // f32 -> bf16 RNE
  unsigned int u = __float_as_uint(f);
  u = u + 0x7FFFu + ((u >> 16) & 1u);
  return (unsigned short)(u >> 16);
}

__device__ inline float gelu_tanh(float u) {           // jax.nn.gelu approximate=True
  float u3 = u * u * u;
  float a  = 0.7978845608028654f * (u + 0.044715f * u3);
  float e  = __expf(2.0f * a);
  float t  = 1.0f - 2.0f / (e + 1.0f);                 // tanh(a), inf-safe
  return 0.5f * u * (1.0f + t);
}

__device__ inline void gload_lds16(const void* g, void* l) {
  __builtin_amdgcn_global_load_lds(
      (const __attribute__((address_space(1))) unsigned int*)g,
      (__attribute__((address_space(3))) unsigned int*)l, 16, 0, 0);
}

__device__ inline float fget(const float4& v, int j) {
  return j == 0 ? v.x : j == 1 ? v.y : j == 2 ? v.z : v.w;
}

// ---------- 1: router ----------
__global__ void router_kernel(const float* __restrict__ x, const float* __restrict__ rw,
                              int* __restrict__ cnt, int* __restrict__ tmp_tok,
                              float* __restrict__ tmp_gate) {
  int tok  = blockIdx.x * 4 + (threadIdx.x >> 6);
  int lane = threadIdx.x & 63;
  const float* xr = x + (size_t)tok * DDIM;
  double acc[NEXP];
#pragma unroll
  for (int e = 0; e < NEXP; e++) acc[e] = 0.0;
  for (int d = lane; d < DDIM; d += 64) {
    double xv = (double)xr[d];
    const float* rp = rw + (size_t)d * NEXP;
#pragma unroll
    for (int e = 0; e < NEXP; e++) acc[e] += xv * (double)rp[e];
  }
#pragma unroll
  for (int off = 32; off >= 1; off >>= 1) {
#pragma unroll
    for (int e = 0; e < NEXP; e++) acc[e] += __shfl_down(acc[e], off, 64);
  }
  if (lane == 0) {
    double mx = acc[0];
    for (int e = 1; e < NEXP; e++) mx = fmax(mx, acc[e]);
    double p[NEXP], sum = 0.0;
    for (int e = 0; e < NEXP; e++) { p[e] = exp(acc[e] - mx); sum += p[e]; }
    for (int e = 0; e < NEXP; e++) p[e] /= sum;
    int i0 = 0;
    for (int e = 1; e < NEXP; e++) if (p[e] > p[i0]) i0 = e;
    int i1 = (i0 == 0) ? 1 : 0;
    for (int e = 0; e < NEXP; e++) if (e != i0 && p[e] > p[i1]) i1 = e;
    int pos0 = atomicAdd(&cnt[i0], 1);
    tmp_tok[i0 * M_TOK + pos0]  = tok;
    tmp_gate[i0 * M_TOK + pos0] = (float)p[i0];
    int pos1 = atomicAdd(&cnt[i1], 1);
    tmp_tok[i1 * M_TOK + pos1]  = tok;
    tmp_gate[i1 * M_TOK + pos1] = (float)p[i1];
  }
}

// ---------- 2: offsets (pad to 128), tile list, compact ----------
__global__ void finalize_kernel(const int* __restrict__ cnt, int* __restrict__ pofs,
                                int* __restrict__ meta, int* __restrict__ tle,
                                int* __restrict__ tlr, int* __restrict__ ptok,
                                float* __restrict__ pgate, const int* __restrict__ tmp_tok,
                                const float* __restrict__ tmp_gate) {
  __shared__ int ofs[NEXP];
  if (threadIdx.x == 0) {
    int o = 0, t = 0;
    for (int e = 0; e < NEXP; e++) {
      ofs[e] = o; pofs[e] = o;
      int nt = (cnt[e] + 127) >> 7;
      for (int i = 0; i < nt; i++) { tle[t] = e; tlr[t] = o + i * 128; t++; }
      o += nt << 7;
    }
    meta[0] = o; meta[1] = t;
  }
  __syncthreads();
  for (int i = threadIdx.x; i < NEXP * M_TOK; i += 256) {
    int e = i >> 11, sl = i & 2047;
    int c = cnt[e];
    int padded = ((c + 127) >> 7) << 7;
    if (sl < padded) {
      int dst = ofs[e] + sl;
      if (sl < c) { ptok[dst] = tmp_tok[i]; pgate[dst] = tmp_gate[i]; }
      else        { ptok[dst] = -1;         pgate[dst] = 0.0f; }
    }
  }
}

// ---------- 3: gather x rows -> bf16 Xg ----------
__global__ void gather_kernel(const float* __restrict__ x, const int* __restrict__ ptok,
                              const int* __restrict__ meta, ushort_t* __restrict__ Xg) {
  int r = blockIdx.x;
  if (r >= meta[0]) return;
  int tok = ptok[r];
  int t = threadIdx.x;
  ushort4 b;
  if (tok >= 0) {
    float4 v = *(const float4*)(x + (size_t)tok * DDIM + t * 4);
    b.x = f2b(v.x); b.y = f2b(v.y); b.z = f2b(v.z); b.w = f2b(v.w);
  } else {
    b.x = 0; b.y = 0; b.z = 0; b.w = 0;
  }
  *(ushort4*)(Xg + (size_t)r * DDIM + t * 4) = b;
}

// ---------- 3b: convert+transpose+fold-scale (z0 selects tensors) ----------
__global__ void convert_kernel(const float* __restrict__ wv, const float* __restrict__ sv,
                               const float* __restrict__ w,  const float* __restrict__ s,
                               const float* __restrict__ w1, const float* __restrict__ s1,
                               ushort_t* __restrict__ WvT, ushort_t* __restrict__ WT,
                               ushort_t* __restrict__ W1T, int z0) {
  int z = z0 + blockIdx.z;
  const float* src   = z == 0 ? wv : z == 1 ? w : w1;
  const float* scale = z == 0 ? sv : z == 1 ? s : s1;
  ushort_t* dst      = z == 0 ? WvT : z == 1 ? WT : W1T;
  int K = z == 2 ? FDIM : DDIM;
  int N = z == 2 ? DDIM : FDIM;

  int e = blockIdx.y;
  int ntn = N >> 7;
  int tk = blockIdx.x / ntn;
  int tn = blockIdx.x - tk * ntn;
  int k0 = tk * 128, n0 = tn * 128;

  const float* S  = src + (size_t)e * K * N + (size_t)k0 * N + n0;
  ushort_t*   D   = dst + (size_t)e * N * K + (size_t)n0 * K + k0;
  const float* sc = scale + (size_t)e * N + n0;

  __shared__ ushort_t lds[128][130];
  unsigned int* L = (unsigned int*)&lds[0][0];

  int t  = threadIdx.x;
  int lg = t >> 4;
  int ll = t & 15;

#pragma unroll
  for (int h = 0; h < 2; h++) {
    int c0 = h * 64 + ll * 4;
    float4 scv = *(const float4*)(sc + c0);
#pragma unroll
    for (int p = 0; p < 4; p++) {
      int r = p * 32 + lg * 2;
      float4 v0 = *(const float4*)(S + (size_t)r * N + c0);
      float4 v1 = *(const float4*)(S + (size_t)(r + 1) * N + c0);
#pragma unroll
      for (int j = 0; j < 4; j++) {
        unsigned int pk = (unsigned int)f2b(fget(v0, j) * fget(scv, j))
                        | ((unsigned int)f2b(fget(v1, j) * fget(scv, j)) << 16);
        L[(c0 + j) * 65 + (r >> 1)] = pk;
      }
    }
  }
  __syncthreads();

#pragma unroll
  for (int q = 0; q < 8; q++) {
    int n  = q * 16 + lg;
    int kc = ll * 8;
    int base = n * 65 + (kc >> 1);
    uint4 o;
    o.x = L[base + 0];
    o.y = L[base + 1];
    o.z = L[base + 2];
    o.w = L[base + 3];
    *(uint4*)(D + (size_t)n * K + kc) = o;
  }
}

// ---------- 4: GEMM1 — depth-3 counted-vmcnt pipeline, A+B via gload_lds ----------
__launch_bounds__(256, 2)
__global__ void gemm1_kernel(const ushort_t* __restrict__ Xg,
                             const ushort_t* __restrict__ WvT, const ushort_t* __restrict__ WT,
                             const int* __restrict__ tle, const int* __restrict__ tlr,
                             const int* __restrict__ meta, ushort_t* __restrict__ G) {
  int b = blockIdx.x;                              // 1280 = 8*160
  int bid = (b & 7) * 160 + (b >> 3);              // bijective XCD chunk swizzle
  int ct = bid / NTMAX;
  int t  = bid - ct * NTMAX;
  if (t >= meta[1]) return;
  int e = tle[t], gr0 = tlr[t];

  __shared__ ushort_t As0[128][32], Bv0[128][32], Bw0[128][32];
  __shared__ ushort_t As1[128][32], Bv1[128][32], Bw1[128][32];
  __shared__ ushort_t As2[128][32], Bv2[128][32], Bw2[128][32];   // 72 KB

  int tid = threadIdx.x, wid = tid >> 6, lane = tid & 63;
  int wr = wid >> 1, wc = wid & 1;
  int srow = wid * 32 + (lane >> 2);
  int scol = (lane & 3) * 8;

  const ushort_t* Ap  = Xg  + (size_t)(gr0 + srow) * DDIM + scol;
  const ushort_t* Bvp = WvT + ((size_t)e * FDIM + ct * 128 + srow) * DDIM + scol;
  const ushort_t* Bwp = WT  + ((size_t)e * FDIM + ct * 128 + srow) * DDIM + scol;

  f32x4 accv[4][4], accy[4][4];
  f32x4 zf = {0.f, 0.f, 0.f, 0.f};
#pragma unroll
  for (int mi = 0; mi < 4; mi++)
#pragma unroll
    for (int ni = 0; ni < 4; ni++) { accv[mi][ni] = zf; accy[mi][ni] = zf; }

  short8 af[4], bvf[4], bwf[4];

#define STG1(As_, Bv_, Bw_, kk) do { if ((kk) < 32) {                            \
    gload_lds16(Ap  + (kk) * 32,             &As_[wid * 32][0]);                 \
    gload_lds16(Ap  + (kk) * 32 + 16 * DDIM, &As_[wid * 32 + 16][0]);            \
    gload_lds16(Bvp + (kk) * 32,             &Bv_[wid * 32][0]);                 \
    gload_lds16(Bvp + (kk) * 32 + 16 * DDIM, &Bv_[wid * 32 + 16][0]);            \
    gload_lds16(Bwp + (kk) * 32,             &Bw_[wid * 32][0]);                 \
    gload_lds16(Bwp + (kk) * 32 + 16 * DDIM, &Bw_[wid * 32 + 16][0]); } }        \
  while (0)

#define RD1(As_, Bv_, Bw_) do {                                                  \
    _Pragma("unroll") for (int mi = 0; mi < 4; mi++)                             \
      af[mi] = *(const short8*)&As_[wr*64 + mi*16 + (lane&15)][(lane>>4)*8];     \
    _Pragma("unroll") for (int ni = 0; ni < 4; ni++) {                           \
      bvf[ni] = *(const short8*)&Bv_[wc*64 + ni*16 + (lane&15)][(lane>>4)*8];    \
      bwf[ni] = *(const short8*)&Bw_[wc*64 + ni*16 + (lane&15)][(lane>>4)*8]; }  \
  } while (0)

#define MM1() do {                                                               \
    _Pragma("unroll") for (int mi = 0; mi < 4; mi++)                             \
      _Pragma("unroll") for (int ni = 0; ni < 4; ni++) {                         \
        accv[mi][ni] = __builtin_amdgcn_mfma_f32_16x16x32_bf16(af[mi], bvf[ni], accv[mi][ni], 0, 0, 0); \
        accy[mi][ni] = __builtin_amdgcn_mfma_f32_16x16x32_bf16(af[mi], bwf[ni], accy[mi][ni], 0, 0, 0); } \
  } while (0)

#define STEP1(As_, Bv_, Bw_, NWAIT, kstage) do {                                 \
    asm volatile("s_waitcnt vmcnt(" #NWAIT ")" ::: "memory");                    \
    __builtin_amdgcn_sched_barrier(0);                                           \
    __builtin_amdgcn_s_barrier();                                                \
    RD1(As_, Bv_, Bw_);                                                          \
    asm volatile("s_waitcnt lgkmcnt(0)" ::: "memory");                           \
    __builtin_amdgcn_sched_barrier(0);                                           \
    __builtin_amdgcn_s_barrier();                                                \
    STG1(As_, Bv_, Bw_, kstage);                                                 \
    MM1();                                                                       \
  } while (0)

  STG1(As0, Bv0, Bw0, 0);
  STG1(As1, Bv1, Bw1, 1);
  STG1(As2, Bv2, Bw2, 2);

  for (int kt = 0; kt < 30; kt += 3) {
    STEP1(As0, Bv0, Bw0, 12, kt + 3);
    STEP1(As1, Bv1, Bw1, 12, kt + 4);
    STEP1(As2, Bv2, Bw2, 12, kt + 5);
  }
  // epilogue: consume 30 (buf0), 31 (buf1); stage 32+ skipped by guard
  STEP1(As0, Bv0, Bw0, 6, 32);
  STEP1(As1, Bv1, Bw1, 0, 32);
#undef STEP1
#undef STG1
#undef RD1
#undef MM1

#pragma unroll
  for (int ni = 0; ni < 4; ni++) {
    int coll = wc * 64 + ni * 16 + (lane & 15);
#pragma unroll
    for (int mi = 0; mi < 4; mi++)
#pragma unroll
      for (int q = 0; q < 4; q++) {
        int rowl = wr * 64 + mi * 16 + (lane >> 4) * 4 + q;
        float g = accv[mi][ni][q] * gelu_tanh(accy[mi][ni][q]);
        G[(size_t)(gr0 + rowl) * FDIM + ct * 128 + coll] = f2b(g);
      }
  }
}

// ---------- 5: GEMM2, K-split x4 — depth-3 counted-vmcnt pipeline ----------
__launch_bounds__(256, 3)
__global__ void gemm2_kernel(const ushort_t* __restrict__ G,
                             const ushort_t* __restrict__ W1T,
                             const int* __restrict__ tle, const int* __restrict__ tlr,
                             const int* __restrict__ meta, const int* __restrict__ ptok,
                             const float* __restrict__ pgate, float* __restrict__ out) {
  int b = blockIdx.x;                              // 1280 = 8*160
  int bid = (b & 7) * 160 + (b >> 3);
  int grp = bid / NTMAX;                           // 0..31 = ct*4+ks
  int t = bid - grp * NTMAX;
  if (t >= meta[1]) return;
  int ct = grp >> 2, ks = grp & 3;
  int e = tle[t], gr0 = tlr[t];
  int k0 = ks * (FDIM / 4);

  __shared__ ushort_t As0[128][32], Bs0[128][32];
  __shared__ ushort_t As1[128][32], Bs1[128][32];
  __shared__ ushort_t As2[128][32], Bs2[128][32];   // 48 KB

  int tid = threadIdx.x, wid = tid >> 6, lane = tid & 63;
  int wr = wid >> 1, wc = wid & 1;
  int srow = wid * 32 + (lane >> 2);
  int scol = (lane & 3) * 8;

  const ushort_t* Ap = G   + (size_t)(gr0 + srow) * FDIM + k0 + scol;
  const ushort_t* Bp = W1T + ((size_t)e * DDIM + ct * 128 + srow) * FDIM + k0 + scol;

  f32x4 acc[4][4];
  f32x4 zf = {0.f, 0.f, 0.f, 0.f};
#pragma unroll
  for (int mi = 0; mi < 4; mi++)
#pragma unroll
    for (int ni = 0; ni < 4; ni++) acc[mi][ni] = zf;

  short8 af[4], bf[4];

#define STG2(As_, Bs_, kk) do { if ((kk) < 32) {                                 \
    gload_lds16(Ap + (kk) * 32,             &As_[wid * 32][0]);                  \
    gload_lds16(Ap + (kk) * 32 + 16 * FDIM, &As_[wid * 32 + 16][0]);             \
    gload_lds16(Bp + (kk) * 32,             &Bs_[wid * 32][0]);                  \
    gload_lds16(Bp + (kk) * 32 + 16 * FDIM, &Bs_[wid * 32 + 16][0]); } }         \
  while (0)

#define RD2(As_, Bs_) do {                                                       \
    _Pragma("unroll") for (int mi = 0; mi < 4; mi++)                             \
      af[mi] = *(const short8*)&As_[wr*64 + mi*16 + (lane&15)][(lane>>4)*8];     \
    _Pragma("unroll") for (int ni = 0; ni < 4; ni++)                             \
      bf[ni] = *(const short8*)&Bs_[wc*64 + ni*16 + (lane&15)][(lane>>4)*8];     \
  } while (0)

#define MM2() do {                                                               \
    _Pragma("unroll") for (int mi = 0; mi < 4; mi++)                             \
      _Pragma("unroll") for (int ni = 0; ni < 4; ni++)                           \
        acc[mi][ni] = __builtin_amdgcn_mfma_f32_16x16x32_bf16(af[mi], bf[ni], acc[mi][ni], 0, 0, 0); \
  } while (0)

#define STEP2(As_, Bs_, NWAIT, kstage) do {                                      \
    asm volatile("s_waitcnt vmcnt(" #NWAIT ")" ::: "memory");                    \
    __builtin_amdgcn_sched_barrier(0);                                           \
    __builtin_amdgcn_s_barrier();                                                \
    RD2(As_, Bs_);                                                               \
    asm volatile("s_waitcnt lgkmcnt(0)" ::: "memory");                           \
    __builtin_amdgcn_sched_barrier(0);                                           \
    __builtin_amdgcn_s_barrier();                                                \
    STG2(As_, Bs_, kstage);                                                      \
    MM2();                                                                       \
  } while (0)

  STG2(As0, Bs0, 0);
  STG2(As1, Bs1, 1);
  STG2(As2, Bs2, 2);

  for (int kt = 0; kt < 30; kt += 3) {
    STEP2(As0, Bs0, 8, kt + 3);
    STEP2(As1, Bs1, 8, kt + 4);
    STEP2(As2, Bs2, 8, kt + 5);
  }
  STEP2(As0, Bs0, 4, 32);
  STEP2(As1, Bs1, 0, 32);
#undef STEP2
#undef STG2
#undef RD2
#undef MM2

#pragma unroll
  for (int ni = 0; ni < 4; ni++) {
    int coll = wc * 64 + ni * 16 + (lane & 15);
#pragma unroll
    for (int mi = 0; mi < 4; mi++)
#pragma unroll
      for (int q = 0; q < 4; q++) {
        int rowl = wr * 64 + mi * 16 + (lane >> 4) * 4 + q;
        int grow = gr0 + rowl;
        int tok  = ptok[grow];
        if (tok >= 0) {
          float val = acc[mi][ni][q] * pgate[grow];
          atomicAdd(out + (size_t)tok * DDIM + ct * 128 + coll, val);
        }
      }
  }
}

// ---------- launch ----------
extern "C" void kernel_launch(void* const* d_in, const int* in_sizes, int n_in,
                              void* d_out, int out_size, void* d_ws, size_t ws_size,
                              hipStream_t stream) {
  const float* x  = (const float*)d_in[0];
  const float* rw = (const float*)d_in[1];
  const float* wv = (const float*)d_in[2];
  const float* sv = (const float*)d_in[3];
  const float* w  = (const float*)d_in[4];
  const float* s  = (const float*)d_in[5];
  const float* w1 = (const float*)d_in[6];
  const float* s1 = (const float*)d_in[7];
  float* out = (float*)d_out;

  char* ws = (char*)d_ws;
  int*   cnt      = (int*)(ws + 0);
  int*   pofs     = (int*)(ws + 64);
  int*   meta     = (int*)(ws + 128);
  int*   tle      = (int*)(ws + 192);
  int*   tlr      = (int*)(ws + 512);
  int*   tmp_tok  = (int*)(ws + 1024);
  float* tmp_gate = (float*)(ws + 66560);
  int*   ptok     = (int*)(ws + 132096);
  float* pgate    = (float*)(ws + 152576);
  ushort_t* Xg    = (ushort_t*)(ws + 173056);      // 10 MB
  ushort_t* G     = (ushort_t*)(ws + 10658816);    // 40 MB
  ushort_t* WvT   = (ushort_t*)(ws + 52601856);    // 64 MB
  ushort_t* WT    = (ushort_t*)(ws + 119710720);   // 64 MB
  ushort_t* W1T   = (ushort_t*)(ws + 186819584);   // 64 MB (end ~242 MB)

  hipMemsetAsync(out, 0, (size_t)out_size * sizeof(float), stream);
  hipMemsetAsync(cnt, 0, NEXP * sizeof(int), stream);
  router_kernel<<<512, 256, 0, stream>>>(x, rw, cnt, tmp_tok, tmp_gate);
  finalize_kernel<<<1, 256, 0, stream>>>(cnt, pofs, meta, tle, tlr, ptok, pgate, tmp_tok, tmp_gate);
  gather_kernel<<<5120, 256, 0, stream>>>(x, ptok, meta, Xg);
  // wv,w converted right before gemm1 (L3-resident weights), w1 right before gemm2
  convert_kernel<<<dim3(256, 8, 2), 256, 0, stream>>>(wv, sv, w, s, w1, s1, WvT, WT, W1T, 0);
  gemm1_kernel<<<1280, 256, 0, stream>>>(Xg, WvT, WT, tle, tlr, meta, G);
  convert_kernel<<<dim3(256, 8, 1), 256, 0, stream>>>(wv, sv, w, s, w1, s1, WvT, WT, W1T, 2);
  gemm2_kernel<<<1280, 256, 0, stream>>>(G, W1T, tle, tlr, meta, ptok, pgate, out);
}

// Round 10
// 389.794 us; speedup vs baseline: 1.4373x; 1.4360x over previous
//
#include <hip/hip_runtime.h>
#include <hip/hip_bf16.h>
#include <math.h>

#define M_TOK 2048
#define DDIM  1024
#define FDIM  4096
#define NEXP  8
#define TOTROWS 5120
#define NTMAX 40

typedef __attribute__((ext_vector_type(8))) short short8;
typedef __attribute__((ext_vector_type(4))) float f32x4;
typedef unsigned short ushort_t;

// ---------- helpers ----------
__device__ inline unsigned short f2b(float f) {        // f32 -> bf16 RNE
  unsigned int u = __float_as_uint(f);
  u = u + 0x7FFFu + ((u >> 16) & 1u);
  return (unsigned short)(u >> 16);
}

__device__ inline float gelu_tanh(float u) {           // jax.nn.gelu approximate=True
  float u3 = u * u * u;
  float a  = 0.7978845608028654f * (u + 0.044715f * u3);
  float e  = __expf(2.0f * a);
  float t  = 1.0f - 2.0f / (e + 1.0f);                 // tanh(a), inf-safe
  return 0.5f * u * (1.0f + t);
}

__device__ inline void gload_lds16(const void* g, void* l) {
  __builtin_amdgcn_global_load_lds(
      (const __attribute__((address_space(1))) unsigned int*)g,
      (__attribute__((address_space(3))) unsigned int*)l, 16, 0, 0);
}

__device__ inline float fget(const float4& v, int j) {
  return j == 0 ? v.x : j == 1 ? v.y : j == 2 ? v.z : v.w;
}

// ---------- convert core: 128x128 tile as two 64-col halves, pair-packed b32 LDS ----------
// dst[e][n][k] = bf16(src[e][k][n] * scale[e][n]);  L = 64*65 uints (16.6 KB)
__device__ inline void convert_tile(const float* __restrict__ src, const float* __restrict__ scale,
                                    ushort_t* __restrict__ dst, int K, int N, int e, int tk, int tn,
                                    unsigned int* L, int t) {
  const float* S  = src + (size_t)e * K * N + (size_t)(tk * 128) * N + tn * 128;
  ushort_t*    D  = dst + (size_t)e * N * K + (size_t)(tn * 128) * K + tk * 128;
  const float* sc = scale + (size_t)e * N + tn * 128;
  int lg = t >> 4, ll = t & 15;
  int c0 = ll * 4;
#pragma unroll
  for (int h = 0; h < 2; h++) {
    float4 scv = *(const float4*)(sc + h * 64 + c0);
#pragma unroll
    for (int i = 0; i < 4; i++) {
      int p = i * 16 + lg;                 // pair-row 0..63
      int r = p * 2;
      float4 v0 = *(const float4*)(S + (size_t)r * N + h * 64 + c0);
      float4 v1 = *(const float4*)(S + (size_t)(r + 1) * N + h * 64 + c0);
#pragma unroll
      for (int j = 0; j < 4; j++) {
        unsigned int pk = (unsigned int)f2b(fget(v0, j) * fget(scv, j))
                        | ((unsigned int)f2b(fget(v1, j) * fget(scv, j)) << 16);
        L[(c0 + j) * 65 + p] = pk;         // bank = (4ll+j+p)%32: 2-way max
      }
    }
    __syncthreads();
#pragma unroll
    for (int q = 0; q < 4; q++) {
      int n = q * 16 + lg;
      int kc = ll * 8;
      unsigned int* base = &L[n * 65 + (kc >> 1)];
      uint4 o;
      o.x = base[0]; o.y = base[1]; o.z = base[2]; o.w = base[3];
      *(uint4*)(D + (size_t)(h * 64 + n) * K + kc) = o;
    }
    __syncthreads();
  }
}

// ---------- K_A: convert(wv,w) 4096 blocks || router 512 blocks ----------
__launch_bounds__(256, 4)
__global__ void conv_router_kernel(const float* __restrict__ wv, const float* __restrict__ sv,
                                   const float* __restrict__ w,  const float* __restrict__ s,
                                   ushort_t* __restrict__ WvT, ushort_t* __restrict__ WT,
                                   const float* __restrict__ x, const float* __restrict__ rw,
                                   int* __restrict__ cnt, int* __restrict__ tmp_tok,
                                   float* __restrict__ tmp_gate, int4* __restrict__ rec_i,
                                   float2* __restrict__ rec_g) {
  __shared__ unsigned int L[64 * 65];
  int b = blockIdx.x;
  if (b < 4096) {
    int z = b >> 11;                        // 0: wv, 1: w
    int bb = b & 2047;
    int e = bb >> 8, rem = bb & 255;
    int tk = rem >> 5, tn = rem & 31;       // K=1024 (8 ktiles), N=4096 (32 ntiles)
    convert_tile(z ? w : wv, z ? s : sv, z ? WT : WvT, DDIM, FDIM, e, tk, tn, L, threadIdx.x);
    return;
  }
  // ---- router path ----
  int tok  = (b - 4096) * 4 + (threadIdx.x >> 6);
  int lane = threadIdx.x & 63;
  const float* xr = x + (size_t)tok * DDIM;
  double acc[NEXP];
#pragma unroll
  for (int e = 0; e < NEXP; e++) acc[e] = 0.0;
  for (int d = lane; d < DDIM; d += 64) {
    double xv = (double)xr[d];
    const float* rp = rw + (size_t)d * NEXP;
#pragma unroll
    for (int e = 0; e < NEXP; e++) acc[e] += xv * (double)rp[e];
  }
#pragma unroll
  for (int off = 32; off >= 1; off >>= 1) {
#pragma unroll
    for (int e = 0; e < NEXP; e++) acc[e] += __shfl_down(acc[e], off, 64);
  }
  if (lane == 0) {
    double mx = acc[0];
    for (int e = 1; e < NEXP; e++) mx = fmax(mx, acc[e]);
    double p[NEXP], sum = 0.0;
    for (int e = 0; e < NEXP; e++) { p[e] = exp(acc[e] - mx); sum += p[e]; }
    for (int e = 0; e < NEXP; e++) p[e] /= sum;
    int i0 = 0;
    for (int e = 1; e < NEXP; e++) if (p[e] > p[i0]) i0 = e;
    int i1 = (i0 == 0) ? 1 : 0;
    for (int e = 0; e < NEXP; e++) if (e != i0 && p[e] > p[i1]) i1 = e;
    int pos0 = atomicAdd(&cnt[i0], 1);
    tmp_tok[i0 * M_TOK + pos0]  = tok;
    tmp_gate[i0 * M_TOK + pos0] = (float)p[i0];
    int pos1 = atomicAdd(&cnt[i1], 1);
    tmp_tok[i1 * M_TOK + pos1]  = tok;
    tmp_gate[i1 * M_TOK + pos1] = (float)p[i1];
    rec_i[tok] = make_int4(i0, pos0, i1, pos1);
    rec_g[tok] = make_float2((float)p[i0], (float)p[i1]);
  }
}

// ---------- convert w1 alone (before gemm2) ----------
__launch_bounds__(256, 4)
__global__ void convw1_kernel(const float* __restrict__ w1, const float* __restrict__ s1,
                              ushort_t* __restrict__ W1T) {
  __shared__ unsigned int L[64 * 65];
  int b = blockIdx.x;                       // 2048
  int e = b >> 8, rem = b & 255;
  int tk = rem >> 3, tn = rem & 7;          // K=4096 (32 ktiles), N=1024 (8 ntiles)
  convert_tile(w1, s1, W1T, FDIM, DDIM, e, tk, tn, L, threadIdx.x);
}

// ---------- 2: offsets (pad to 128), tile list, compact ----------
__global__ void finalize_kernel(const int* __restrict__ cnt, int* __restrict__ pofs,
                                int* __restrict__ meta, int* __restrict__ tle,
                                int* __restrict__ tlr, int* __restrict__ ptok,
                                const int* __restrict__ tmp_tok) {
  __shared__ int ofs[NEXP];
  if (threadIdx.x == 0) {
    int o = 0, t = 0;
    for (int e = 0; e < NEXP; e++) {
      ofs[e] = o; pofs[e] = o;
      int nt = (cnt[e] + 127) >> 7;
      for (int i = 0; i < nt; i++) { tle[t] = e; tlr[t] = o + i * 128; t++; }
      o += nt << 7;
    }
    meta[0] = o; meta[1] = t;
  }
  __syncthreads();
  for (int i = threadIdx.x; i < NEXP * M_TOK; i += 256) {
    int e = i >> 11, sl = i & 2047;
    int c = cnt[e];
    int padded = ((c + 127) >> 7) << 7;
    if (sl < padded) {
      int dst = ofs[e] + sl;
      ptok[dst] = (sl < c) ? tmp_tok[i] : -1;
    }
  }
}

// ---------- 3: gather x rows -> bf16 Xg ----------
__global__ void gather_kernel(const float* __restrict__ x, const int* __restrict__ ptok,
                              const int* __restrict__ meta, ushort_t* __restrict__ Xg) {
  int r = blockIdx.x;
  if (r >= meta[0]) return;
  int tok = ptok[r];
  int t = threadIdx.x;
  ushort4 b;
  if (tok >= 0) {
    float4 v = *(const float4*)(x + (size_t)tok * DDIM + t * 4);
    b.x = f2b(v.x); b.y = f2b(v.y); b.z = f2b(v.z); b.w = f2b(v.w);
  } else {
    b.x = 0; b.y = 0; b.z = 0; b.w = 0;
  }
  *(ushort4*)(Xg + (size_t)r * DDIM + t * 4) = b;
}

// ---------- 4: GEMM1 fused (R3 proven structure): G = (Xg@WvT) * gelu(Xg@WT) ----------
__launch_bounds__(256, 2)
__global__ void gemm1_kernel(const ushort_t* __restrict__ Xg,
                             const ushort_t* __restrict__ WvT, const ushort_t* __restrict__ WT,
                             const int* __restrict__ tle, const int* __restrict__ tlr,
                             const int* __restrict__ meta, ushort_t* __restrict__ G) {
  int b = blockIdx.x;                              // 1280 = 8*160
  int bid = (b & 7) * 160 + (b >> 3);              // bijective XCD chunk swizzle
  int ct = bid / NTMAX;
  int t  = bid - ct * NTMAX;
  if (t >= meta[1]) return;
  int e = tle[t], gr0 = tlr[t];

  __shared__ ushort_t As[128][32];
  __shared__ ushort_t Bv[128][32];
  __shared__ ushort_t Bw[128][32];

  int tid = threadIdx.x, wid = tid >> 6, lane = tid & 63;
  int wr = wid >> 1, wc = wid & 1;
  int srow = wid * 32 + (lane >> 2);
  int scol = (lane & 3) * 8;

  const ushort_t* Ap  = Xg  + (size_t)(gr0 + srow) * DDIM + scol;
  const ushort_t* Bvp = WvT + ((size_t)e * FDIM + ct * 128 + srow) * DDIM + scol;
  const ushort_t* Bwp = WT  + ((size_t)e * FDIM + ct * 128 + srow) * DDIM + scol;

  f32x4 accv[4][4], accy[4][4];
  f32x4 zf = {0.f, 0.f, 0.f, 0.f};
#pragma unroll
  for (int mi = 0; mi < 4; mi++)
#pragma unroll
    for (int ni = 0; ni < 4; ni++) { accv[mi][ni] = zf; accy[mi][ni] = zf; }

  for (int kt = 0; kt < DDIM / 32; kt++) {
    __syncthreads();
    gload_lds16(Ap  + kt * 32,             &As[wid * 32][0]);
    gload_lds16(Ap  + kt * 32 + 16 * DDIM, &As[wid * 32 + 16][0]);
    gload_lds16(Bvp + kt * 32,             &Bv[wid * 32][0]);
    gload_lds16(Bvp + kt * 32 + 16 * DDIM, &Bv[wid * 32 + 16][0]);
    gload_lds16(Bwp + kt * 32,             &Bw[wid * 32][0]);
    gload_lds16(Bwp + kt * 32 + 16 * DDIM, &Bw[wid * 32 + 16][0]);
    __syncthreads();

    short8 af[4], bvf[4], bwf[4];
#pragma unroll
    for (int mi = 0; mi < 4; mi++)
      af[mi] = *(const short8*)&As[wr * 64 + mi * 16 + (lane & 15)][(lane >> 4) * 8];
#pragma unroll
    for (int ni = 0; ni < 4; ni++) {
      bvf[ni] = *(const short8*)&Bv[wc * 64 + ni * 16 + (lane & 15)][(lane >> 4) * 8];
      bwf[ni] = *(const short8*)&Bw[wc * 64 + ni * 16 + (lane & 15)][(lane >> 4) * 8];
    }
#pragma unroll
    for (int mi = 0; mi < 4; mi++)
#pragma unroll
      for (int ni = 0; ni < 4; ni++) {
        accv[mi][ni] = __builtin_amdgcn_mfma_f32_16x16x32_bf16(af[mi], bvf[ni], accv[mi][ni], 0, 0, 0);
        accy[mi][ni] = __builtin_amdgcn_mfma_f32_16x16x32_bf16(af[mi], bwf[ni], accy[mi][ni], 0, 0, 0);
      }
  }

#pragma unroll
  for (int ni = 0; ni < 4; ni++) {
    int coll = wc * 64 + ni * 16 + (lane & 15);
#pragma unroll
    for (int mi = 0; mi < 4; mi++)
#pragma unroll
      for (int q = 0; q < 4; q++) {
        int rowl = wr * 64 + mi * 16 + (lane >> 4) * 4 + q;
        float g = accv[mi][ni][q] * gelu_tanh(accy[mi][ni][q]);
        G[(size_t)(gr0 + rowl) * FDIM + ct * 128 + coll] = f2b(g);
      }
  }
}

// ---------- 5: GEMM2 (R3 structure, K-split x2) -> partial buffers, NO atomics ----------
__launch_bounds__(256, 3)
__global__ void gemm2_kernel(const ushort_t* __restrict__ G,
                             const ushort_t* __restrict__ W1T,
                             const int* __restrict__ tle, const int* __restrict__ tlr,
                             const int* __restrict__ meta,
                             float* __restrict__ P0, float* __restrict__ P1) {
  int b = blockIdx.x;                              // 640 = 8*80
  int bid = (b & 7) * 80 + (b >> 3);
  int grp = bid / NTMAX;                           // 0..15 = ct*2+ks
  int t = bid - grp * NTMAX;
  if (t >= meta[1]) return;
  int ct = grp >> 1, ks = grp & 1;
  int e = tle[t], gr0 = tlr[t];
  int k0 = ks * (FDIM / 2);
  float* P = ks ? P1 : P0;

  __shared__ ushort_t As[128][32];
  __shared__ ushort_t Bs[128][32];

  int tid = threadIdx.x, wid = tid >> 6, lane = tid & 63;
  int wr = wid >> 1, wc = wid & 1;
  int srow = wid * 32 + (lane >> 2);
  int scol = (lane & 3) * 8;

  const ushort_t* Ap = G   + (size_t)(gr0 + srow) * FDIM + k0 + scol;
  const ushort_t* Bp = W1T + ((size_t)e * DDIM + ct * 128 + srow) * FDIM + k0 + scol;

  f32x4 acc[4][4];
  f32x4 zf = {0.f, 0.f, 0.f, 0.f};
#pragma unroll
  for (int mi = 0; mi < 4; mi++)
#pragma unroll
    for (int ni = 0; ni < 4; ni++) acc[mi][ni] = zf;

  for (int kt = 0; kt < (FDIM / 2) / 32; kt++) {
    __syncthreads();
    gload_lds16(Ap + kt * 32,             &As[wid * 32][0]);
    gload_lds16(Ap + kt * 32 + 16 * FDIM, &As[wid * 32 + 16][0]);
    gload_lds16(Bp + kt * 32,             &Bs[wid * 32][0]);
    gload_lds16(Bp + kt * 32 + 16 * FDIM, &Bs[wid * 32 + 16][0]);
    __syncthreads();

    short8 af[4], bf[4];
#pragma unroll
    for (int mi = 0; mi < 4; mi++)
      af[mi] = *(const short8*)&As[wr * 64 + mi * 16 + (lane & 15)][(lane >> 4) * 8];
#pragma unroll
    for (int ni = 0; ni < 4; ni++)
      bf[ni] = *(const short8*)&Bs[wc * 64 + ni * 16 + (lane & 15)][(lane >> 4) * 8];
#pragma unroll
    for (int mi = 0; mi < 4; mi++)
#pragma unroll
      for (int ni = 0; ni < 4; ni++)
        acc[mi][ni] = __builtin_amdgcn_mfma_f32_16x16x32_bf16(af[mi], bf[ni], acc[mi][ni], 0, 0, 0);
  }

#pragma unroll
  for (int ni = 0; ni < 4; ni++) {
    int coll = wc * 64 + ni * 16 + (lane & 15);
#pragma unroll
    for (int mi = 0; mi < 4; mi++)
#pragma unroll
      for (int q = 0; q < 4; q++) {
        int rowl = wr * 64 + mi * 16 + (lane >> 4) * 4 + q;
        P[(size_t)(gr0 + rowl) * DDIM + ct * 128 + coll] = acc[mi][ni][q];
      }
  }
}

// ---------- 6: combine: out[tok] = g0*(P0+P1)[row0] + g1*(P0+P1)[row1] ----------
__global__ void combine_kernel(const float* __restrict__ P0, const float* __restrict__ P1,
                               const int4* __restrict__ rec_i, const float2* __restrict__ rec_g,
                               const int* __restrict__ pofs, float* __restrict__ out) {
  int tok = blockIdx.x;
  int c = threadIdx.x * 4;
  int4 ri = rec_i[tok];
  float2 rg = rec_g[tok];
  size_t r0 = (size_t)(pofs[ri.x] + ri.y) * DDIM + c;
  size_t r1 = (size_t)(pofs[ri.z] + ri.w) * DDIM + c;
  float4 a0 = *(const float4*)(P0 + r0);
  float4 b0 = *(const float4*)(P1 + r0);
  float4 a1 = *(const float4*)(P0 + r1);
  float4 b1 = *(const float4*)(P1 + r1);
  float4 o;
  o.x = rg.x * (a0.x + b0.x) + rg.y * (a1.x + b1.x);
  o.y = rg.x * (a0.y + b0.y) + rg.y * (a1.y + b1.y);
  o.z = rg.x * (a0.z + b0.z) + rg.y * (a1.z + b1.z);
  o.w = rg.x * (a0.w + b0.w) + rg.y * (a1.w + b1.w);
  *(float4*)(out + (size_t)tok * DDIM + c) = o;
}

// ---------- launch ----------
extern "C" void kernel_launch(void* const* d_in, const int* in_sizes, int n_in,
                              void* d_out, int out_size, void* d_ws, size_t ws_size,
                              hipStream_t stream) {
  const float* x  = (const float*)d_in[0];
  const float* rw = (const float*)d_in[1];
  const float* wv = (const float*)d_in[2];
  const float* sv = (const float*)d_in[3];
  const float* w  = (const float*)d_in[4];
  const float* s  = (const float*)d_in[5];
  const float* w1 = (const float*)d_in[6];
  const float* s1 = (const float*)d_in[7];
  float* out = (float*)d_out;

  char* ws = (char*)d_ws;
  int*    cnt      = (int*)(ws + 0);
  int*    pofs     = (int*)(ws + 64);
  int*    meta     = (int*)(ws + 128);
  int*    tle      = (int*)(ws + 192);
  int*    tlr      = (int*)(ws + 1024);
  int*    tmp_tok  = (int*)(ws + 2048);
  float*  tmp_gate = (float*)(ws + 67584);
  int*    ptok     = (int*)(ws + 133120);
  int4*   rec_i    = (int4*)(ws + 174080);
  float2* rec_g    = (float2*)(ws + 206848);
  ushort_t* Xg     = (ushort_t*)(ws + 223232);       // 10 MB
  ushort_t* G      = (ushort_t*)(ws + 10708992);     // 40 MB
  ushort_t* WvT    = (ushort_t*)(ws + 52652032);     // 64 MB (dead after gemm1)
  ushort_t* WT     = (ushort_t*)(ws + 119760896);    // 64 MB
  ushort_t* W1T    = (ushort_t*)(ws + 186869760);    // 64 MB (end ~242 MB)
  float*  P0       = (float*)(ws + 52652032);        // overlay old WvT (20 MB)
  float*  P1       = (float*)(ws + 73623552);        // overlay old WvT (20 MB)

  hipMemsetAsync(cnt, 0, NEXP * sizeof(int), stream);
  conv_router_kernel<<<4608, 256, 0, stream>>>(wv, sv, w, s, WvT, WT, x, rw,
                                               cnt, tmp_tok, tmp_gate, rec_i, rec_g);
  finalize_kernel<<<1, 256, 0, stream>>>(cnt, pofs, meta, tle, tlr, ptok, tmp_tok);
  gather_kernel<<<5120, 256, 0, stream>>>(x, ptok, meta, Xg);
  gemm1_kernel<<<1280, 256, 0, stream>>>(Xg, WvT, WT, tle, tlr, meta, G);
  convw1_kernel<<<2048, 256, 0, stream>>>(w1, s1, W1T);
  gemm2_kernel<<<640, 256, 0, stream>>>(G, W1T, tle, tlr, meta, P0, P1);
  combine_kernel<<<2048, 256, 0, stream>>>(P0, P1, rec_i, rec_g, pofs, out);
}

// Round 11
// 377.223 us; speedup vs baseline: 1.4852x; 1.0333x over previous
//
#include <hip/hip_runtime.h>
#include <hip/hip_bf16.h>
#include <math.h>

#define M_TOK 2048
#define DDIM  1024
#define FDIM  4096
#define NEXP  8
#define TOTROWS 5120
#define NTMAX 40

typedef __attribute__((ext_vector_type(8))) short short8;
typedef __attribute__((ext_vector_type(4))) float f32x4;
typedef unsigned short ushort_t;

// ---------- helpers ----------
__device__ inline unsigned short f2b(float f) {        // f32 -> bf16 RNE
  unsigned int u = __float_as_uint(f);
  u = u + 0x7FFFu + ((u >> 16) & 1u);
  return (unsigned short)(u >> 16);
}

__device__ inline float gelu_tanh(float u) {           // jax.nn.gelu approximate=True
  float u3 = u * u * u;
  float a  = 0.7978845608028654f * (u + 0.044715f * u3);
  float e  = __expf(2.0f * a);
  float t  = 1.0f - 2.0f / (e + 1.0f);                 // tanh(a), inf-safe
  return 0.5f * u * (1.0f + t);
}

__device__ inline void gload_lds16(const void* g, void* l) {
  __builtin_amdgcn_global_load_lds(
      (const __attribute__((address_space(1))) unsigned int*)g,
      (__attribute__((address_space(3))) unsigned int*)l, 16, 0, 0);
}

__device__ inline float fget(const float4& v, int j) {
  return j == 0 ? v.x : j == 1 ? v.y : j == 2 ? v.z : v.w;
}

// ---------- convert core: ONE 128k x 64n half-tile per block, 1 barrier ----------
// dst[e][n][k] = bf16(src[e][k][n] * scale[e][n]);  L = 64*65 uints (16.6 KB)
__device__ inline void convert_half(const float* __restrict__ src, const float* __restrict__ scale,
                                    ushort_t* __restrict__ dst, int K, int N, int e, int tk, int tn,
                                    int h, unsigned int* L, int t) {
  const float* S  = src + (size_t)e * K * N + (size_t)(tk * 128) * N + tn * 128 + h * 64;
  ushort_t*    D  = dst + (size_t)e * N * K + (size_t)(tn * 128 + h * 64) * K + tk * 128;
  const float* sc = scale + (size_t)e * N + tn * 128 + h * 64;
  int lg = t >> 4, ll = t & 15;
  int c0 = ll * 4;
  float4 scv = *(const float4*)(sc + c0);
#pragma unroll
  for (int i = 0; i < 4; i++) {
    int p = i * 16 + lg;                   // pair-row 0..63
    int r = p * 2;
    float4 v0 = *(const float4*)(S + (size_t)r * N + c0);
    float4 v1 = *(const float4*)(S + (size_t)(r + 1) * N + c0);
#pragma unroll
    for (int j = 0; j < 4; j++) {
      unsigned int pk = (unsigned int)f2b(fget(v0, j) * fget(scv, j))
                      | ((unsigned int)f2b(fget(v1, j) * fget(scv, j)) << 16);
      L[(c0 + j) * 65 + p] = pk;           // bank = (4ll+j+16i+lg)%32: 2-way, free
    }
  }
  __syncthreads();
#pragma unroll
  for (int q = 0; q < 4; q++) {
    int n = q * 16 + lg;
    int kc = ll * 8;
    unsigned int* base = &L[n * 65 + (kc >> 1)];
    uint4 o;
    o.x = base[0]; o.y = base[1]; o.z = base[2]; o.w = base[3];
    *(uint4*)(D + (size_t)n * K + kc) = o;
  }
}

// ---------- K_A: convert(wv,w) 8192 half-blocks || router 512 blocks ----------
__launch_bounds__(256, 8)
__global__ void conv_router_kernel(const float* __restrict__ wv, const float* __restrict__ sv,
                                   const float* __restrict__ w,  const float* __restrict__ s,
                                   ushort_t* __restrict__ WvT, ushort_t* __restrict__ WT,
                                   const float* __restrict__ x, const float* __restrict__ rw,
                                   int* __restrict__ cnt, int* __restrict__ tmp_tok,
                                   int4* __restrict__ rec_i, float2* __restrict__ rec_g) {
  __shared__ unsigned int L[64 * 65];
  int b = blockIdx.x;
  if (b < 8192) {
    int z = b >> 12;                        // 0: wv, 1: w
    int bb = b & 4095;
    int e = bb >> 9, rem = bb & 511;
    int tk = rem >> 6, tn = (rem >> 1) & 31, h = rem & 1;   // K=1024, N=4096
    convert_half(z ? w : wv, z ? s : sv, z ? WT : WvT, DDIM, FDIM, e, tk, tn, h, L, threadIdx.x);
    return;
  }
  // ---- router path ----
  int tok  = (b - 8192) * 4 + (threadIdx.x >> 6);
  int lane = threadIdx.x & 63;
  const float* xr = x + (size_t)tok * DDIM;
  double acc[NEXP];
#pragma unroll
  for (int e = 0; e < NEXP; e++) acc[e] = 0.0;
  for (int d = lane; d < DDIM; d += 64) {
    double xv = (double)xr[d];
    const float* rp = rw + (size_t)d * NEXP;
#pragma unroll
    for (int e = 0; e < NEXP; e++) acc[e] += xv * (double)rp[e];
  }
#pragma unroll
  for (int off = 32; off >= 1; off >>= 1) {
#pragma unroll
    for (int e = 0; e < NEXP; e++) acc[e] += __shfl_down(acc[e], off, 64);
  }
  if (lane == 0) {
    double mx = acc[0];
    for (int e = 1; e < NEXP; e++) mx = fmax(mx, acc[e]);
    double p[NEXP], sum = 0.0;
    for (int e = 0; e < NEXP; e++) { p[e] = exp(acc[e] - mx); sum += p[e]; }
    for (int e = 0; e < NEXP; e++) p[e] /= sum;
    int i0 = 0;
    for (int e = 1; e < NEXP; e++) if (p[e] > p[i0]) i0 = e;
    int i1 = (i0 == 0) ? 1 : 0;
    for (int e = 0; e < NEXP; e++) if (e != i0 && p[e] > p[i1]) i1 = e;
    int pos0 = atomicAdd(&cnt[i0], 1);
    tmp_tok[i0 * M_TOK + pos0] = tok;
    int pos1 = atomicAdd(&cnt[i1], 1);
    tmp_tok[i1 * M_TOK + pos1] = tok;
    rec_i[tok] = make_int4(i0, pos0, i1, pos1);
    rec_g[tok] = make_float2((float)p[i0], (float)p[i1]);
  }
}

// ---------- convert w1 alone (before gemm2): 4096 half-blocks ----------
__launch_bounds__(256, 8)
__global__ void convw1_kernel(const float* __restrict__ w1, const float* __restrict__ s1,
                              ushort_t* __restrict__ W1T) {
  __shared__ unsigned int L[64 * 65];
  int b = blockIdx.x;                       // 4096
  int e = b >> 9, rem = b & 511;
  int tk = rem >> 4, tn = (rem >> 1) & 7, h = rem & 1;      // K=4096, N=1024
  convert_half(w1, s1, W1T, FDIM, DDIM, e, tk, tn, h, L, threadIdx.x);
}

// ---------- 2: offsets (pad to 128), tile list, compact ----------
__global__ void finalize_kernel(const int* __restrict__ cnt, int* __restrict__ pofs,
                                int* __restrict__ meta, int* __restrict__ tle,
                                int* __restrict__ tlr, int* __restrict__ ptok,
                                const int* __restrict__ tmp_tok) {
  __shared__ int ofs[NEXP];
  if (threadIdx.x == 0) {
    int o = 0, t = 0;
    for (int e = 0; e < NEXP; e++) {
      ofs[e] = o; pofs[e] = o;
      int nt = (cnt[e] + 127) >> 7;
      for (int i = 0; i < nt; i++) { tle[t] = e; tlr[t] = o + i * 128; t++; }
      o += nt << 7;
    }
    meta[0] = o; meta[1] = t;
  }
  __syncthreads();
  for (int i = threadIdx.x; i < NEXP * M_TOK; i += 256) {
    int e = i >> 11, sl = i & 2047;
    int c = cnt[e];
    int padded = ((c + 127) >> 7) << 7;
    if (sl < padded) {
      int dst = ofs[e] + sl;
      ptok[dst] = (sl < c) ? tmp_tok[i] : -1;
    }
  }
}

// ---------- 3: gather x rows -> bf16 Xg ----------
__global__ void gather_kernel(const float* __restrict__ x, const int* __restrict__ ptok,
                              const int* __restrict__ meta, ushort_t* __restrict__ Xg) {
  int r = blockIdx.x;
  if (r >= meta[0]) return;
  int tok = ptok[r];
  int t = threadIdx.x;
  ushort4 b;
  if (tok >= 0) {
    float4 v = *(const float4*)(x + (size_t)tok * DDIM + t * 4);
    b.x = f2b(v.x); b.y = f2b(v.y); b.z = f2b(v.z); b.w = f2b(v.w);
  } else {
    b.x = 0; b.y = 0; b.z = 0; b.w = 0;
  }
  *(ushort4*)(Xg + (size_t)r * DDIM + t * 4) = b;
}

// ---------- 4: GEMM1 — R5-proven depth-2 counted-vmcnt pipeline ----------
__launch_bounds__(256, 2)
__global__ void gemm1_kernel(const ushort_t* __restrict__ Xg,
                             const ushort_t* __restrict__ WvT, const ushort_t* __restrict__ WT,
                             const int* __restrict__ tle, const int* __restrict__ tlr,
                             const int* __restrict__ meta, ushort_t* __restrict__ G) {
  int b = blockIdx.x;                              // 1280 = 8*160
  int bid = (b & 7) * 160 + (b >> 3);              // bijective XCD chunk swizzle
  int ct = bid / NTMAX;
  int t  = bid - ct * NTMAX;
  if (t >= meta[1]) return;
  int e = tle[t], gr0 = tlr[t];

  __shared__ ushort_t As0[128][32], Bv0[128][32], Bw0[128][32];
  __shared__ ushort_t As1[128][32], Bv1[128][32], Bw1[128][32];

  int tid = threadIdx.x, wid = tid >> 6, lane = tid & 63;
  int wr = wid >> 1, wc = wid & 1;
  int srow = wid * 32 + (lane >> 2);
  int scol = (lane & 3) * 8;

  const ushort_t* Ap  = Xg  + (size_t)(gr0 + srow) * DDIM + scol;
  const ushort_t* Bvp = WvT + ((size_t)e * FDIM + ct * 128 + srow) * DDIM + scol;
  const ushort_t* Bwp = WT  + ((size_t)e * FDIM + ct * 128 + srow) * DDIM + scol;

  f32x4 accv[4][4], accy[4][4];
  f32x4 zf = {0.f, 0.f, 0.f, 0.f};
#pragma unroll
  for (int mi = 0; mi < 4; mi++)
#pragma unroll
    for (int ni = 0; ni < 4; ni++) { accv[mi][ni] = zf; accy[mi][ni] = zf; }

  short8 af[4], bvf[4], bwf[4];

#define STG1(As_, Bv_, Bw_, kk) do {                                             \
    gload_lds16(Ap  + (kk) * 32,             &As_[wid * 32][0]);                 \
    gload_lds16(Ap  + (kk) * 32 + 16 * DDIM, &As_[wid * 32 + 16][0]);            \
    gload_lds16(Bvp + (kk) * 32,             &Bv_[wid * 32][0]);                 \
    gload_lds16(Bvp + (kk) * 32 + 16 * DDIM, &Bv_[wid * 32 + 16][0]);            \
    gload_lds16(Bwp + (kk) * 32,             &Bw_[wid * 32][0]);                 \
    gload_lds16(Bwp + (kk) * 32 + 16 * DDIM, &Bw_[wid * 32 + 16][0]);            \
  } while (0)

#define RD1(As_, Bv_, Bw_) do {                                                  \
    _Pragma("unroll") for (int mi = 0; mi < 4; mi++)                             \
      af[mi] = *(const short8*)&As_[wr*64 + mi*16 + (lane&15)][(lane>>4)*8];     \
    _Pragma("unroll") for (int ni = 0; ni < 4; ni++) {                           \
      bvf[ni] = *(const short8*)&Bv_[wc*64 + ni*16 + (lane&15)][(lane>>4)*8];    \
      bwf[ni] = *(const short8*)&Bw_[wc*64 + ni*16 + (lane&15)][(lane>>4)*8]; }  \
  } while (0)

#define MM1() do {                                                               \
    _Pragma("unroll") for (int mi = 0; mi < 4; mi++)                             \
      _Pragma("unroll") for (int ni = 0; ni < 4; ni++) {                         \
        accv[mi][ni] = __builtin_amdgcn_mfma_f32_16x16x32_bf16(af[mi], bvf[ni], accv[mi][ni], 0, 0, 0); \
        accy[mi][ni] = __builtin_amdgcn_mfma_f32_16x16x32_bf16(af[mi], bwf[ni], accy[mi][ni], 0, 0, 0); } \
  } while (0)

  STG1(As0, Bv0, Bw0, 0);
  STG1(As1, Bv1, Bw1, 1);

  for (int kt = 0; kt < 30; kt += 2) {
    asm volatile("s_waitcnt vmcnt(6)" ::: "memory");
    __builtin_amdgcn_sched_barrier(0);
    __builtin_amdgcn_s_barrier();
    RD1(As0, Bv0, Bw0);
    asm volatile("s_waitcnt lgkmcnt(0)" ::: "memory");
    __builtin_amdgcn_sched_barrier(0);
    __builtin_amdgcn_s_barrier();
    STG1(As0, Bv0, Bw0, kt + 2);
    MM1();
    asm volatile("s_waitcnt vmcnt(6)" ::: "memory");
    __builtin_amdgcn_sched_barrier(0);
    __builtin_amdgcn_s_barrier();
    RD1(As1, Bv1, Bw1);
    asm volatile("s_waitcnt lgkmcnt(0)" ::: "memory");
    __builtin_amdgcn_sched_barrier(0);
    __builtin_amdgcn_s_barrier();
    STG1(As1, Bv1, Bw1, kt + 3);
    MM1();
  }
  asm volatile("s_waitcnt vmcnt(6)" ::: "memory");
  __builtin_amdgcn_sched_barrier(0);
  __builtin_amdgcn_s_barrier();
  RD1(As0, Bv0, Bw0);
  MM1();
  asm volatile("s_waitcnt vmcnt(0)" ::: "memory");
  __builtin_amdgcn_sched_barrier(0);
  __builtin_amdgcn_s_barrier();
  RD1(As1, Bv1, Bw1);
  MM1();
#undef STG1
#undef RD1
#undef MM1

#pragma unroll
  for (int ni = 0; ni < 4; ni++) {
    int coll = wc * 64 + ni * 16 + (lane & 15);
#pragma unroll
    for (int mi = 0; mi < 4; mi++)
#pragma unroll
      for (int q = 0; q < 4; q++) {
        int rowl = wr * 64 + mi * 16 + (lane >> 4) * 4 + q;
        float g = accv[mi][ni][q] * gelu_tanh(accy[mi][ni][q]);
        G[(size_t)(gr0 + rowl) * FDIM + ct * 128 + coll] = f2b(g);
      }
  }
}

// ---------- 5: GEMM2 — depth-2 counted-vmcnt, K-split x2, P0/P1 stores ----------
__launch_bounds__(256, 3)
__global__ void gemm2_kernel(const ushort_t* __restrict__ G,
                             const ushort_t* __restrict__ W1T,
                             const int* __restrict__ tle, const int* __restrict__ tlr,
                             const int* __restrict__ meta,
                             float* __restrict__ P0, float* __restrict__ P1) {
  int b = blockIdx.x;                              // 640 = 8*80
  int bid = (b & 7) * 80 + (b >> 3);
  int grp = bid / NTMAX;                           // 0..15 = ct*2+ks
  int t = bid - grp * NTMAX;
  if (t >= meta[1]) return;
  int ct = grp >> 1, ks = grp & 1;
  int e = tle[t], gr0 = tlr[t];
  int k0 = ks * (FDIM / 2);
  float* P = ks ? P1 : P0;

  __shared__ ushort_t As0[128][32], Bs0[128][32];
  __shared__ ushort_t As1[128][32], Bs1[128][32];

  int tid = threadIdx.x, wid = tid >> 6, lane = tid & 63;
  int wr = wid >> 1, wc = wid & 1;
  int srow = wid * 32 + (lane >> 2);
  int scol = (lane & 3) * 8;

  const ushort_t* Ap = G   + (size_t)(gr0 + srow) * FDIM + k0 + scol;
  const ushort_t* Bp = W1T + ((size_t)e * DDIM + ct * 128 + srow) * FDIM + k0 + scol;

  f32x4 acc[4][4];
  f32x4 zf = {0.f, 0.f, 0.f, 0.f};
#pragma unroll
  for (int mi = 0; mi < 4; mi++)
#pragma unroll
    for (int ni = 0; ni < 4; ni++) acc[mi][ni] = zf;

  short8 af[4], bf[4];

#define STG2(As_, Bs_, kk) do {                                                  \
    gload_lds16(Ap + (kk) * 32,             &As_[wid * 32][0]);                  \
    gload_lds16(Ap + (kk) * 32 + 16 * FDIM, &As_[wid * 32 + 16][0]);             \
    gload_lds16(Bp + (kk) * 32,             &Bs_[wid * 32][0]);                  \
    gload_lds16(Bp + (kk) * 32 + 16 * FDIM, &Bs_[wid * 32 + 16][0]);             \
  } while (0)

#define RD2(As_, Bs_) do {                                                       \
    _Pragma("unroll") for (int mi = 0; mi < 4; mi++)                             \
      af[mi] = *(const short8*)&As_[wr*64 + mi*16 + (lane&15)][(lane>>4)*8];     \
    _Pragma("unroll") for (int ni = 0; ni < 4; ni++)                             \
      bf[ni] = *(const short8*)&Bs_[wc*64 + ni*16 + (lane&15)][(lane>>4)*8];     \
  } while (0)

#define MM2() do {                                                               \
    _Pragma("unroll") for (int mi = 0; mi < 4; mi++)                             \
      _Pragma("unroll") for (int ni = 0; ni < 4; ni++)                           \
        acc[mi][ni] = __builtin_amdgcn_mfma_f32_16x16x32_bf16(af[mi], bf[ni], acc[mi][ni], 0, 0, 0); \
  } while (0)

  STG2(As0, Bs0, 0);
  STG2(As1, Bs1, 1);

  for (int kt = 0; kt < 62; kt += 2) {
    asm volatile("s_waitcnt vmcnt(4)" ::: "memory");
    __builtin_amdgcn_sched_barrier(0);
    __builtin_amdgcn_s_barrier();
    RD2(As0, Bs0);
    asm volatile("s_waitcnt lgkmcnt(0)" ::: "memory");
    __builtin_amdgcn_sched_barrier(0);
    __builtin_amdgcn_s_barrier();
    STG2(As0, Bs0, kt + 2);
    MM2();
    asm volatile("s_waitcnt vmcnt(4)" ::: "memory");
    __builtin_amdgcn_sched_barrier(0);
    __builtin_amdgcn_s_barrier();
    RD2(As1, Bs1);
    asm volatile("s_waitcnt lgkmcnt(0)" ::: "memory");
    __builtin_amdgcn_sched_barrier(0);
    __builtin_amdgcn_s_barrier();
    STG2(As1, Bs1, kt + 3);
    MM2();
  }
  asm volatile("s_waitcnt vmcnt(4)" ::: "memory");
  __builtin_amdgcn_sched_barrier(0);
  __builtin_amdgcn_s_barrier();
  RD2(As0, Bs0);
  MM2();
  asm volatile("s_waitcnt vmcnt(0)" ::: "memory");
  __builtin_amdgcn_sched_barrier(0);
  __builtin_amdgcn_s_barrier();
  RD2(As1, Bs1);
  MM2();
#undef STG2
#undef RD2
#undef MM2

#pragma unroll
  for (int ni = 0; ni < 4; ni++) {
    int coll = wc * 64 + ni * 16 + (lane & 15);
#pragma unroll
    for (int mi = 0; mi < 4; mi++)
#pragma unroll
      for (int q = 0; q < 4; q++) {
        int rowl = wr * 64 + mi * 16 + (lane >> 4) * 4 + q;
        P[(size_t)(gr0 + rowl) * DDIM + ct * 128 + coll] = acc[mi][ni][q];
      }
  }
}

// ---------- 6: combine: out[tok] = g0*(P0+P1)[row0] + g1*(P0+P1)[row1] ----------
__global__ void combine_kernel(const float* __restrict__ P0, const float* __restrict__ P1,
                               const int4* __restrict__ rec_i, const float2* __restrict__ rec_g,
                               const int* __restrict__ pofs, float* __restrict__ out) {
  int tok = blockIdx.x;
  int c = threadIdx.x * 4;
  int4 ri = rec_i[tok];
  float2 rg = rec_g[tok];
  size_t r0 = (size_t)(pofs[ri.x] + ri.y) * DDIM + c;
  size_t r1 = (size_t)(pofs[ri.z] + ri.w) * DDIM + c;
  float4 a0 = *(const float4*)(P0 + r0);
  float4 b0 = *(const float4*)(P1 + r0);
  float4 a1 = *(const float4*)(P0 + r1);
  float4 b1 = *(const float4*)(P1 + r1);
  float4 o;
  o.x = rg.x * (a0.x + b0.x) + rg.y * (a1.x + b1.x);
  o.y = rg.x * (a0.y + b0.y) + rg.y * (a1.y + b1.y);
  o.z = rg.x * (a0.z + b0.z) + rg.y * (a1.z + b1.z);
  o.w = rg.x * (a0.w + b0.w) + rg.y * (a1.w + b1.w);
  *(float4*)(out + (size_t)tok * DDIM + c) = o;
}

// ---------- launch ----------
extern "C" void kernel_launch(void* const* d_in, const int* in_sizes, int n_in,
                              void* d_out, int out_size, void* d_ws, size_t ws_size,
                              hipStream_t stream) {
  const float* x  = (const float*)d_in[0];
  const float* rw = (const float*)d_in[1];
  const float* wv = (const float*)d_in[2];
  const float* sv = (const float*)d_in[3];
  const float* w  = (const float*)d_in[4];
  const float* s  = (const float*)d_in[5];
  const float* w1 = (const float*)d_in[6];
  const float* s1 = (const float*)d_in[7];
  float* out = (float*)d_out;

  char* ws = (char*)d_ws;
  int*    cnt      = (int*)(ws + 0);
  int*    pofs     = (int*)(ws + 64);
  int*    meta     = (int*)(ws + 128);
  int*    tle      = (int*)(ws + 192);
  int*    tlr      = (int*)(ws + 1024);
  int*    tmp_tok  = (int*)(ws + 2048);
  int*    ptok     = (int*)(ws + 133120);
  int4*   rec_i    = (int4*)(ws + 174080);
  float2* rec_g    = (float2*)(ws + 206848);
  ushort_t* Xg     = (ushort_t*)(ws + 223232);       // 10 MB
  ushort_t* G      = (ushort_t*)(ws + 10708992);     // 40 MB
  ushort_t* WvT    = (ushort_t*)(ws + 52652032);     // 64 MB (dead after gemm1)
  ushort_t* WT     = (ushort_t*)(ws + 119760896);    // 64 MB
  ushort_t* W1T    = (ushort_t*)(ws + 186869760);    // 64 MB (end ~242 MB)
  float*  P0       = (float*)(ws + 52652032);        // overlay old WvT (20 MB)
  float*  P1       = (float*)(ws + 73623552);        // overlay old WvT (20 MB)

  hipMemsetAsync(cnt, 0, NEXP * sizeof(int), stream);
  conv_router_kernel<<<8704, 256, 0, stream>>>(wv, sv, w, s, WvT, WT, x, rw,
                                               cnt, tmp_tok, rec_i, rec_g);
  finalize_kernel<<<1, 256, 0, stream>>>(cnt, pofs, meta, tle, tlr, ptok, tmp_tok);
  gather_kernel<<<5120, 256, 0, stream>>>(x, ptok, meta, Xg);
  gemm1_kernel<<<1280, 256, 0, stream>>>(Xg, WvT, WT, tle, tlr, meta, G);
  convw1_kernel<<<4096, 256, 0, stream>>>(w1, s1, W1T);
  gemm2_kernel<<<640, 256, 0, stream>>>(G, W1T, tle, tlr, meta, P0, P1);
  combine_kernel<<<2048, 256, 0, stream>>>(P0, P1, rec_i, rec_g, pofs, out);
}

// Round 12
// 375.774 us; speedup vs baseline: 1.4909x; 1.0039x over previous
//
#include <hip/hip_runtime.h>
#include <hip/hip_bf16.h>
#include <math.h>

#define M_TOK 2048
#define DDIM  1024
#define FDIM  4096
#define NEXP  8
#define TOTROWS 5120
#define NTMAX 40

typedef __attribute__((ext_vector_type(8))) short short8;
typedef __attribute__((ext_vector_type(4))) float f32x4;
typedef unsigned short ushort_t;

// ---------- helpers ----------
__device__ inline unsigned short f2b(float f) {        // f32 -> bf16 RNE
  unsigned int u = __float_as_uint(f);
  u = u + 0x7FFFu + ((u >> 16) & 1u);
  return (unsigned short)(u >> 16);
}

__device__ inline float gelu_tanh(float u) {           // jax.nn.gelu approximate=True
  float u3 = u * u * u;
  float a  = 0.7978845608028654f * (u + 0.044715f * u3);
  float e  = __expf(2.0f * a);
  float t  = 1.0f - 2.0f / (e + 1.0f);                 // tanh(a), inf-safe
  return 0.5f * u * (1.0f + t);
}

__device__ inline void gload_lds16(const void* g, void* l) {
  __builtin_amdgcn_global_load_lds(
      (const __attribute__((address_space(1))) unsigned int*)g,
      (__attribute__((address_space(3))) unsigned int*)l, 16, 0, 0);
}

__device__ inline float fget(const float4& v, int j) {
  return j == 0 ? v.x : j == 1 ? v.y : j == 2 ? v.z : v.w;
}

// ---------- convert core: 128k x 64n half-tile -> TILED dst [e][K/128][N][128] ----------
// Writes are ONE contiguous 16 KB region per block (DRAM-row friendly).
__device__ inline void convert_half(const float* __restrict__ src, const float* __restrict__ scale,
                                    ushort_t* __restrict__ dst, int K, int N, int e, int tk, int n0,
                                    unsigned int* L, int t) {
  const float* S  = src + (size_t)e * K * N + (size_t)(tk * 128) * N + n0;
  ushort_t*    Dt = dst + ((size_t)(e * (K >> 7) + tk) * N + n0) * 128;
  const float* sc = scale + (size_t)e * N + n0;
  int lg = t >> 4, ll = t & 15;
  int c0 = ll * 4;
  float4 scv = *(const float4*)(sc + c0);
#pragma unroll
  for (int i = 0; i < 4; i++) {
    int p = i * 16 + lg;                   // pair-row 0..63
    int r = p * 2;
    float4 v0 = *(const float4*)(S + (size_t)r * N + c0);
    float4 v1 = *(const float4*)(S + (size_t)(r + 1) * N + c0);
#pragma unroll
    for (int j = 0; j < 4; j++) {
      unsigned int pk = (unsigned int)f2b(fget(v0, j) * fget(scv, j))
                      | ((unsigned int)f2b(fget(v1, j) * fget(scv, j)) << 16);
      L[(c0 + j) * 65 + p] = pk;           // bank = (4ll+j+16i+lg)%32: 2-way, free
    }
  }
  __syncthreads();
#pragma unroll
  for (int q = 0; q < 4; q++) {
    int nl = q * 16 + lg;                  // 0..63
    int kc = ll * 8;                       // 0..120
    unsigned int* base = &L[nl * 65 + (kc >> 1)];
    uint4 o;
    o.x = base[0]; o.y = base[1]; o.z = base[2]; o.w = base[3];
    *(uint4*)(Dt + (size_t)nl * 128 + kc) = o;   // contiguous 256B/row, 16KB/block
  }
}

// ---------- K_A: convert(wv,w) 8192 half-blocks || router 512 blocks ----------
__launch_bounds__(256, 8)
__global__ void conv_router_kernel(const float* __restrict__ wv, const float* __restrict__ sv,
                                   const float* __restrict__ w,  const float* __restrict__ s,
                                   ushort_t* __restrict__ WvT, ushort_t* __restrict__ WT,
                                   const float* __restrict__ x, const float* __restrict__ rw,
                                   int* __restrict__ cnt, int* __restrict__ tmp_tok,
                                   int4* __restrict__ rec_i, float2* __restrict__ rec_g) {
  __shared__ unsigned int L[64 * 65];
  int b = blockIdx.x;
  if (b < 8192) {
    int z = b >> 12;                        // 0: wv, 1: w
    int bb = b & 4095;
    int e = bb >> 9, rem = bb & 511;
    int tk = rem >> 6, n0 = (rem & 63) * 64;            // K=1024: 8 ktiles; N=4096: 64 slabs
    convert_half(z ? w : wv, z ? s : sv, z ? WT : WvT, DDIM, FDIM, e, tk, n0, L, threadIdx.x);
    return;
  }
  // ---- router path ----
  int tok  = (b - 8192) * 4 + (threadIdx.x >> 6);
  int lane = threadIdx.x & 63;
  const float* xr = x + (size_t)tok * DDIM;
  double acc[NEXP];
#pragma unroll
  for (int e = 0; e < NEXP; e++) acc[e] = 0.0;
  for (int d = lane; d < DDIM; d += 64) {
    double xv = (double)xr[d];
    const float* rp = rw + (size_t)d * NEXP;
#pragma unroll
    for (int e = 0; e < NEXP; e++) acc[e] += xv * (double)rp[e];
  }
#pragma unroll
  for (int off = 32; off >= 1; off >>= 1) {
#pragma unroll
    for (int e = 0; e < NEXP; e++) acc[e] += __shfl_down(acc[e], off, 64);
  }
  if (lane == 0) {
    double mx = acc[0];
    for (int e = 1; e < NEXP; e++) mx = fmax(mx, acc[e]);
    double p[NEXP], sum = 0.0;
    for (int e = 0; e < NEXP; e++) { p[e] = exp(acc[e] - mx); sum += p[e]; }
    for (int e = 0; e < NEXP; e++) p[e] /= sum;
    int i0 = 0;
    for (int e = 1; e < NEXP; e++) if (p[e] > p[i0]) i0 = e;
    int i1 = (i0 == 0) ? 1 : 0;
    for (int e = 0; e < NEXP; e++) if (e != i0 && p[e] > p[i1]) i1 = e;
    int pos0 = atomicAdd(&cnt[i0], 1);
    tmp_tok[i0 * M_TOK + pos0] = tok;
    int pos1 = atomicAdd(&cnt[i1], 1);
    tmp_tok[i1 * M_TOK + pos1] = tok;
    rec_i[tok] = make_int4(i0, pos0, i1, pos1);
    rec_g[tok] = make_float2((float)p[i0], (float)p[i1]);
  }
}

// ---------- convert w1 alone (before gemm2): 4096 half-blocks ----------
__launch_bounds__(256, 8)
__global__ void convw1_kernel(const float* __restrict__ w1, const float* __restrict__ s1,
                              ushort_t* __restrict__ W1T) {
  __shared__ unsigned int L[64 * 65];
  int b = blockIdx.x;                       // 4096
  int e = b >> 9, rem = b & 511;
  int tk = rem >> 4, n0 = (rem & 15) * 64;              // K=4096: 32 ktiles; N=1024: 16 slabs
  convert_half(w1, s1, W1T, FDIM, DDIM, e, tk, n0, L, threadIdx.x);
}

// ---------- 2: offsets (pad to 128), tile list, compact ----------
__global__ void finalize_kernel(const int* __restrict__ cnt, int* __restrict__ pofs,
                                int* __restrict__ meta, int* __restrict__ tle,
                                int* __restrict__ tlr, int* __restrict__ ptok,
                                const int* __restrict__ tmp_tok) {
  __shared__ int ofs[NEXP];
  if (threadIdx.x == 0) {
    int o = 0, t = 0;
    for (int e = 0; e < NEXP; e++) {
      ofs[e] = o; pofs[e] = o;
      int nt = (cnt[e] + 127) >> 7;
      for (int i = 0; i < nt; i++) { tle[t] = e; tlr[t] = o + i * 128; t++; }
      o += nt << 7;
    }
    meta[0] = o; meta[1] = t;
  }
  __syncthreads();
  for (int i = threadIdx.x; i < NEXP * M_TOK; i += 256) {
    int e = i >> 11, sl = i & 2047;
    int c = cnt[e];
    int padded = ((c + 127) >> 7) << 7;
    if (sl < padded) {
      int dst = ofs[e] + sl;
      ptok[dst] = (sl < c) ? tmp_tok[i] : -1;
    }
  }
}

// ---------- 3: gather x rows -> bf16 Xg ----------
__global__ void gather_kernel(const float* __restrict__ x, const int* __restrict__ ptok,
                              const int* __restrict__ meta, ushort_t* __restrict__ Xg) {
  int r = blockIdx.x;
  if (r >= meta[0]) return;
  int tok = ptok[r];
  int t = threadIdx.x;
  ushort4 b;
  if (tok >= 0) {
    float4 v = *(const float4*)(x + (size_t)tok * DDIM + t * 4);
    b.x = f2b(v.x); b.y = f2b(v.y); b.z = f2b(v.z); b.w = f2b(v.w);
  } else {
    b.x = 0; b.y = 0; b.z = 0; b.w = 0;
  }
  *(ushort4*)(Xg + (size_t)r * DDIM + t * 4) = b;
}

// ---------- 4: GEMM1 — depth-2 counted-vmcnt pipeline, tiled-B addressing ----------
__launch_bounds__(256, 2)
__global__ void gemm1_kernel(const ushort_t* __restrict__ Xg,
                             const ushort_t* __restrict__ WvT, const ushort_t* __restrict__ WT,
                             const int* __restrict__ tle, const int* __restrict__ tlr,
                             const int* __restrict__ meta, ushort_t* __restrict__ G) {
  int b = blockIdx.x;                              // 1280 = 8*160
  int bid = (b & 7) * 160 + (b >> 3);              // bijective XCD chunk swizzle
  int ct = bid / NTMAX;
  int t  = bid - ct * NTMAX;
  if (t >= meta[1]) return;
  int e = tle[t], gr0 = tlr[t];

  __shared__ ushort_t As0[128][32], Bv0[128][32], Bw0[128][32];
  __shared__ ushort_t As1[128][32], Bv1[128][32], Bw1[128][32];

  int tid = threadIdx.x, wid = tid >> 6, lane = tid & 63;
  int wr = wid >> 1, wc = wid & 1;
  int srow = wid * 32 + (lane >> 2);
  int scol = (lane & 3) * 8;

  const ushort_t* Ap  = Xg + (size_t)(gr0 + srow) * DDIM + scol;
  // tiled layout: W'[e][k/128][n:4096][128]
  const ushort_t* Bvp = WvT + ((size_t)(e * 8) * FDIM + ct * 128 + srow) * 128 + scol;
  const ushort_t* Bwp = WT  + ((size_t)(e * 8) * FDIM + ct * 128 + srow) * 128 + scol;
#define BOFF1(kk) ((size_t)((kk) >> 2) * (FDIM * 128) + ((kk) & 3) * 32)

  f32x4 accv[4][4], accy[4][4];
  f32x4 zf = {0.f, 0.f, 0.f, 0.f};
#pragma unroll
  for (int mi = 0; mi < 4; mi++)
#pragma unroll
    for (int ni = 0; ni < 4; ni++) { accv[mi][ni] = zf; accy[mi][ni] = zf; }

  short8 af[4], bvf[4], bwf[4];

#define STG1(As_, Bv_, Bw_, kk) do {                                             \
    gload_lds16(Ap  + (kk) * 32,             &As_[wid * 32][0]);                 \
    gload_lds16(Ap  + (kk) * 32 + 16 * DDIM, &As_[wid * 32 + 16][0]);            \
    gload_lds16(Bvp + BOFF1(kk),             &Bv_[wid * 32][0]);                 \
    gload_lds16(Bvp + BOFF1(kk) + 2048,      &Bv_[wid * 32 + 16][0]);            \
    gload_lds16(Bwp + BOFF1(kk),             &Bw_[wid * 32][0]);                 \
    gload_lds16(Bwp + BOFF1(kk) + 2048,      &Bw_[wid * 32 + 16][0]);            \
  } while (0)

#define RD1(As_, Bv_, Bw_) do {                                                  \
    _Pragma("unroll") for (int mi = 0; mi < 4; mi++)                             \
      af[mi] = *(const short8*)&As_[wr*64 + mi*16 + (lane&15)][(lane>>4)*8];     \
    _Pragma("unroll") for (int ni = 0; ni < 4; ni++) {                           \
      bvf[ni] = *(const short8*)&Bv_[wc*64 + ni*16 + (lane&15)][(lane>>4)*8];    \
      bwf[ni] = *(const short8*)&Bw_[wc*64 + ni*16 + (lane&15)][(lane>>4)*8]; }  \
  } while (0)

#define MM1() do {                                                               \
    _Pragma("unroll") for (int mi = 0; mi < 4; mi++)                             \
      _Pragma("unroll") for (int ni = 0; ni < 4; ni++) {                         \
        accv[mi][ni] = __builtin_amdgcn_mfma_f32_16x16x32_bf16(af[mi], bvf[ni], accv[mi][ni], 0, 0, 0); \
        accy[mi][ni] = __builtin_amdgcn_mfma_f32_16x16x32_bf16(af[mi], bwf[ni], accy[mi][ni], 0, 0, 0); } \
  } while (0)

  STG1(As0, Bv0, Bw0, 0);
  STG1(As1, Bv1, Bw1, 1);

  for (int kt = 0; kt < 30; kt += 2) {
    asm volatile("s_waitcnt vmcnt(6)" ::: "memory");
    __builtin_amdgcn_sched_barrier(0);
    __builtin_amdgcn_s_barrier();
    RD1(As0, Bv0, Bw0);
    asm volatile("s_waitcnt lgkmcnt(0)" ::: "memory");
    __builtin_amdgcn_sched_barrier(0);
    __builtin_amdgcn_s_barrier();
    STG1(As0, Bv0, Bw0, kt + 2);
    MM1();
    asm volatile("s_waitcnt vmcnt(6)" ::: "memory");
    __builtin_amdgcn_sched_barrier(0);
    __builtin_amdgcn_s_barrier();
    RD1(As1, Bv1, Bw1);
    asm volatile("s_waitcnt lgkmcnt(0)" ::: "memory");
    __builtin_amdgcn_sched_barrier(0);
    __builtin_amdgcn_s_barrier();
    STG1(As1, Bv1, Bw1, kt + 3);
    MM1();
  }
  asm volatile("s_waitcnt vmcnt(6)" ::: "memory");
  __builtin_amdgcn_sched_barrier(0);
  __builtin_amdgcn_s_barrier();
  RD1(As0, Bv0, Bw0);
  MM1();
  asm volatile("s_waitcnt vmcnt(0)" ::: "memory");
  __builtin_amdgcn_sched_barrier(0);
  __builtin_amdgcn_s_barrier();
  RD1(As1, Bv1, Bw1);
  MM1();
#undef STG1
#undef RD1
#undef MM1

#pragma unroll
  for (int ni = 0; ni < 4; ni++) {
    int coll = wc * 64 + ni * 16 + (lane & 15);
#pragma unroll
    for (int mi = 0; mi < 4; mi++)
#pragma unroll
      for (int q = 0; q < 4; q++) {
        int rowl = wr * 64 + mi * 16 + (lane >> 4) * 4 + q;
        float g = accv[mi][ni][q] * gelu_tanh(accy[mi][ni][q]);
        G[(size_t)(gr0 + rowl) * FDIM + ct * 128 + coll] = f2b(g);
      }
  }
}

// ---------- 5: GEMM2 — depth-2 counted-vmcnt, K-split x2, tiled-B, P0/P1 stores ----------
__launch_bounds__(256, 3)
__global__ void gemm2_kernel(const ushort_t* __restrict__ G,
                             const ushort_t* __restrict__ W1T,
                             const int* __restrict__ tle, const int* __restrict__ tlr,
                             const int* __restrict__ meta,
                             float* __restrict__ P0, float* __restrict__ P1) {
  int b = blockIdx.x;                              // 640 = 8*80
  int bid = (b & 7) * 80 + (b >> 3);
  int grp = bid / NTMAX;                           // 0..15 = ct*2+ks
  int t = bid - grp * NTMAX;
  if (t >= meta[1]) return;
  int ct = grp >> 1, ks = grp & 1;
  int e = tle[t], gr0 = tlr[t];
  int k0 = ks * (FDIM / 2);
  float* P = ks ? P1 : P0;

  __shared__ ushort_t As0[128][32], Bs0[128][32];
  __shared__ ushort_t As1[128][32], Bs1[128][32];

  int tid = threadIdx.x, wid = tid >> 6, lane = tid & 63;
  int wr = wid >> 1, wc = wid & 1;
  int srow = wid * 32 + (lane >> 2);
  int scol = (lane & 3) * 8;

  const ushort_t* Ap = G + (size_t)(gr0 + srow) * FDIM + k0 + scol;
  // tiled layout: W1'[e][k/128: 32][n:1024][128]; ks half starts at ktile e*32+ks*16
  const ushort_t* Bp = W1T + ((size_t)(e * 32 + ks * 16) * DDIM + ct * 128 + srow) * 128 + scol;
#define BOFF2(kk) ((size_t)((kk) >> 2) * (DDIM * 128) + ((kk) & 3) * 32)

  f32x4 acc[4][4];
  f32x4 zf = {0.f, 0.f, 0.f, 0.f};
#pragma unroll
  for (int mi = 0; mi < 4; mi++)
#pragma unroll
    for (int ni = 0; ni < 4; ni++) acc[mi][ni] = zf;

  short8 af[4], bf[4];

#define STG2(As_, Bs_, kk) do {                                                  \
    gload_lds16(Ap + (kk) * 32,             &As_[wid * 32][0]);                  \
    gload_lds16(Ap + (kk) * 32 + 16 * FDIM, &As_[wid * 32 + 16][0]);             \
    gload_lds16(Bp + BOFF2(kk),             &Bs_[wid * 32][0]);                  \
    gload_lds16(Bp + BOFF2(kk) + 2048,      &Bs_[wid * 32 + 16][0]);             \
  } while (0)

#define RD2(As_, Bs_) do {                                                       \
    _Pragma("unroll") for (int mi = 0; mi < 4; mi++)                             \
      af[mi] = *(const short8*)&As_[wr*64 + mi*16 + (lane&15)][(lane>>4)*8];     \
    _Pragma("unroll") for (int ni = 0; ni < 4; ni++)                             \
      bf[ni] = *(const short8*)&Bs_[wc*64 + ni*16 + (lane&15)][(lane>>4)*8];     \
  } while (0)

#define MM2() do {                                                               \
    _Pragma("unroll") for (int mi = 0; mi < 4; mi++)                             \
      _Pragma("unroll") for (int ni = 0; ni < 4; ni++)                           \
        acc[mi][ni] = __builtin_amdgcn_mfma_f32_16x16x32_bf16(af[mi], bf[ni], acc[mi][ni], 0, 0, 0); \
  } while (0)

  STG2(As0, Bs0, 0);
  STG2(As1, Bs1, 1);

  for (int kt = 0; kt < 62; kt += 2) {
    asm volatile("s_waitcnt vmcnt(4)" ::: "memory");
    __builtin_amdgcn_sched_barrier(0);
    __builtin_amdgcn_s_barrier();
    RD2(As0, Bs0);
    asm volatile("s_waitcnt lgkmcnt(0)" ::: "memory");
    __builtin_amdgcn_sched_barrier(0);
    __builtin_amdgcn_s_barrier();
    STG2(As0, Bs0, kt + 2);
    MM2();
    asm volatile("s_waitcnt vmcnt(4)" ::: "memory");
    __builtin_amdgcn_sched_barrier(0);
    __builtin_amdgcn_s_barrier();
    RD2(As1, Bs1);
    asm volatile("s_waitcnt lgkmcnt(0)" ::: "memory");
    __builtin_amdgcn_sched_barrier(0);
    __builtin_amdgcn_s_barrier();
    STG2(As1, Bs1, kt + 3);
    MM2();
  }
  asm volatile("s_waitcnt vmcnt(4)" ::: "memory");
  __builtin_amdgcn_sched_barrier(0);
  __builtin_amdgcn_s_barrier();
  RD2(As0, Bs0);
  MM2();
  asm volatile("s_waitcnt vmcnt(0)" ::: "memory");
  __builtin_amdgcn_sched_barrier(0);
  __builtin_amdgcn_s_barrier();
  RD2(As1, Bs1);
  MM2();
#undef STG2
#undef RD2
#undef MM2

#pragma unroll
  for (int ni = 0; ni < 4; ni++) {
    int coll = wc * 64 + ni * 16 + (lane & 15);
#pragma unroll
    for (int mi = 0; mi < 4; mi++)
#pragma unroll
      for (int q = 0; q < 4; q++) {
        int rowl = wr * 64 + mi * 16 + (lane >> 4) * 4 + q;
        P[(size_t)(gr0 + rowl) * DDIM + ct * 128 + coll] = acc[mi][ni][q];
      }
  }
}

// ---------- 6: combine: out[tok] = g0*(P0+P1)[row0] + g1*(P0+P1)[row1] ----------
__global__ void combine_kernel(const float* __restrict__ P0, const float* __restrict__ P1,
                               const int4* __restrict__ rec_i, const float2* __restrict__ rec_g,
                               const int* __restrict__ pofs, float* __restrict__ out) {
  int tok = blockIdx.x;
  int c = threadIdx.x * 4;
  int4 ri = rec_i[tok];
  float2 rg = rec_g[tok];
  size_t r0 = (size_t)(pofs[ri.x] + ri.y) * DDIM + c;
  size_t r1 = (size_t)(pofs[ri.z] + ri.w) * DDIM + c;
  float4 a0 = *(const float4*)(P0 + r0);
  float4 b0 = *(const float4*)(P1 + r0);
  float4 a1 = *(const float4*)(P0 + r1);
  float4 b1 = *(const float4*)(P1 + r1);
  float4 o;
  o.x = rg.x * (a0.x + b0.x) + rg.y * (a1.x + b1.x);
  o.y = rg.x * (a0.y + b0.y) + rg.y * (a1.y + b1.y);
  o.z = rg.x * (a0.z + b0.z) + rg.y * (a1.z + b1.z);
  o.w = rg.x * (a0.w + b0.w) + rg.y * (a1.w + b1.w);
  *(float4*)(out + (size_t)tok * DDIM + c) = o;
}

// ---------- launch ----------
extern "C" void kernel_launch(void* const* d_in, const int* in_sizes, int n_in,
                              void* d_out, int out_size, void* d_ws, size_t ws_size,
                              hipStream_t stream) {
  const float* x  = (const float*)d_in[0];
  const float* rw = (const float*)d_in[1];
  const float* wv = (const float*)d_in[2];
  const float* sv = (const float*)d_in[3];
  const float* w  = (const float*)d_in[4];
  const float* s  = (const float*)d_in[5];
  const float* w1 = (const float*)d_in[6];
  const float* s1 = (const float*)d_in[7];
  float* out = (float*)d_out;

  char* ws = (char*)d_ws;
  int*    cnt      = (int*)(ws + 0);
  int*    pofs     = (int*)(ws + 64);
  int*    meta     = (int*)(ws + 128);
  int*    tle      = (int*)(ws + 192);
  int*    tlr      = (int*)(ws + 1024);
  int*    tmp_tok  = (int*)(ws + 2048);
  int*    ptok     = (int*)(ws + 133120);
  int4*   rec_i    = (int4*)(ws + 174080);
  float2* rec_g    = (float2*)(ws + 206848);
  ushort_t* Xg     = (ushort_t*)(ws + 223232);       // 10 MB
  ushort_t* G      = (ushort_t*)(ws + 10708992);     // 40 MB
  ushort_t* WvT    = (ushort_t*)(ws + 52652032);     // 64 MB (dead after gemm1)
  ushort_t* WT     = (ushort_t*)(ws + 119760896);    // 64 MB
  ushort_t* W1T    = (ushort_t*)(ws + 186869760);    // 64 MB (end ~242 MB)
  float*  P0       = (float*)(ws + 52652032);        // overlay old WvT (20 MB)
  float*  P1       = (float*)(ws + 73623552);        // overlay old WvT (20 MB)

  hipMemsetAsync(cnt, 0, NEXP * sizeof(int), stream);
  conv_router_kernel<<<8704, 256, 0, stream>>>(wv, sv, w, s, WvT, WT, x, rw,
                                               cnt, tmp_tok, rec_i, rec_g);
  finalize_kernel<<<1, 256, 0, stream>>>(cnt, pofs, meta, tle, tlr, ptok, tmp_tok);
  gather_kernel<<<5120, 256, 0, stream>>>(x, ptok, meta, Xg);
  gemm1_kernel<<<1280, 256, 0, stream>>>(Xg, WvT, WT, tle, tlr, meta, G);
  convw1_kernel<<<4096, 256, 0, stream>>>(w1, s1, W1T);
  gemm2_kernel<<<640, 256, 0, stream>>>(G, W1T, tle, tlr, meta, P0, P1);
  combine_kernel<<<2048, 256, 0, stream>>>(P0, P1, rec_i, rec_g, pofs, out);
}

// Round 13
// 369.255 us; speedup vs baseline: 1.5172x; 1.0177x over previous
//
#include <hip/hip_runtime.h>
#include <hip/hip_bf16.h>
#include <math.h>

#define M_TOK 2048
#define DDIM  1024
#define FDIM  4096
#define NEXP  8
#define TOTROWS 5120
#define NTMAX 40

typedef __attribute__((ext_vector_type(8))) short short8;
typedef __attribute__((ext_vector_type(4))) float f32x4;
typedef unsigned short ushort_t;

// ---------- helpers ----------
__device__ inline unsigned short f2b(float f) {        // f32 -> bf16 RNE
  unsigned int u = __float_as_uint(f);
  u = u + 0x7FFFu + ((u >> 16) & 1u);
  return (unsigned short)(u >> 16);
}

__device__ inline float gelu_tanh(float u) {           // jax.nn.gelu approximate=True
  float u3 = u * u * u;
  float a  = 0.7978845608028654f * (u + 0.044715f * u3);
  float e  = __expf(2.0f * a);
  float t  = 1.0f - 2.0f / (e + 1.0f);                 // tanh(a), inf-safe
  return 0.5f * u * (1.0f + t);
}

__device__ inline void gload_lds16(const void* g, void* l) {
  __builtin_amdgcn_global_load_lds(
      (const __attribute__((address_space(1))) unsigned int*)g,
      (__attribute__((address_space(3))) unsigned int*)l, 16, 0, 0);
}

__device__ inline float fget(const float4& v, int j) {
  return j == 0 ? v.x : j == 1 ? v.y : j == 2 ? v.z : v.w;
}

// ---------- convert core: 128k x 64n half-tile -> TILED dst [e][K/128][N][128] ----------
// All 8 global loads hoisted into regs first (MLP), then convert+LDS, then 16KB store.
__device__ inline void convert_half(const float* __restrict__ src, const float* __restrict__ scale,
                                    ushort_t* __restrict__ dst, int K, int N, int e, int tk, int n0,
                                    unsigned int* L, int t) {
  const float* S  = src + (size_t)e * K * N + (size_t)(tk * 128) * N + n0;
  ushort_t*    Dt = dst + ((size_t)(e * (K >> 7) + tk) * N + n0) * 128;
  const float* sc = scale + (size_t)e * N + n0;
  int lg = t >> 4, ll = t & 15;
  int c0 = ll * 4;
  float4 scv = *(const float4*)(sc + c0);

  float4 v0[4], v1[4];                     // 8 loads in flight (32 VGPR)
#pragma unroll
  for (int i = 0; i < 4; i++) {
    int r = (i * 16 + lg) * 2;
    v0[i] = *(const float4*)(S + (size_t)r * N + c0);
    v1[i] = *(const float4*)(S + (size_t)(r + 1) * N + c0);
  }
#pragma unroll
  for (int i = 0; i < 4; i++) {
    int p = i * 16 + lg;                   // pair-row 0..63
#pragma unroll
    for (int j = 0; j < 4; j++) {
      unsigned int pk = (unsigned int)f2b(fget(v0[i], j) * fget(scv, j))
                      | ((unsigned int)f2b(fget(v1[i], j) * fget(scv, j)) << 16);
      L[(c0 + j) * 65 + p] = pk;           // bank = (4ll+j+16i+lg)%32: 2-way, free
    }
  }
  __syncthreads();
#pragma unroll
  for (int q = 0; q < 4; q++) {
    int nl = q * 16 + lg;                  // 0..63
    int kc = ll * 8;                       // 0..120
    unsigned int* base = &L[nl * 65 + (kc >> 1)];
    uint4 o;
    o.x = base[0]; o.y = base[1]; o.z = base[2]; o.w = base[3];
    *(uint4*)(Dt + (size_t)nl * 128 + kc) = o;   // contiguous 256B/row, 16KB/block
  }
}

// ---------- K_A: convert(wv,w,w1) 12288 half-blocks || router 512 blocks ----------
__launch_bounds__(256, 4)
__global__ void conv_router_kernel(const float* __restrict__ wv, const float* __restrict__ sv,
                                   const float* __restrict__ w,  const float* __restrict__ s,
                                   const float* __restrict__ w1, const float* __restrict__ s1,
                                   ushort_t* __restrict__ WvT, ushort_t* __restrict__ WT,
                                   ushort_t* __restrict__ W1T,
                                   const float* __restrict__ x, const float* __restrict__ rw,
                                   int* __restrict__ cnt, int* __restrict__ tmp_tok,
                                   int4* __restrict__ rec_i, float2* __restrict__ rec_g) {
  __shared__ unsigned int L[64 * 65];
  int b = blockIdx.x;
  if (b < 12288) {
    int z = b >> 12;                        // 0: wv, 1: w, 2: w1
    int bb = b & 4095;
    int e = bb >> 9, rem = bb & 511;
    if (z == 2) {
      int tk = rem >> 4, n0 = (rem & 15) * 64;          // K=4096: 32 ktiles; N=1024: 16 slabs
      convert_half(w1, s1, W1T, FDIM, DDIM, e, tk, n0, L, threadIdx.x);
    } else {
      int tk = rem >> 6, n0 = (rem & 63) * 64;          // K=1024: 8 ktiles; N=4096: 64 slabs
      convert_half(z ? w : wv, z ? s : sv, z ? WT : WvT, DDIM, FDIM, e, tk, n0, L, threadIdx.x);
    }
    return;
  }
  // ---- router path ----
  int tok  = (b - 12288) * 4 + (threadIdx.x >> 6);
  int lane = threadIdx.x & 63;
  const float* xr = x + (size_t)tok * DDIM;
  double acc[NEXP];
#pragma unroll
  for (int e = 0; e < NEXP; e++) acc[e] = 0.0;
  for (int d = lane; d < DDIM; d += 64) {
    double xv = (double)xr[d];
    const float* rp = rw + (size_t)d * NEXP;
#pragma unroll
    for (int e = 0; e < NEXP; e++) acc[e] += xv * (double)rp[e];
  }
#pragma unroll
  for (int off = 32; off >= 1; off >>= 1) {
#pragma unroll
    for (int e = 0; e < NEXP; e++) acc[e] += __shfl_down(acc[e], off, 64);
  }
  if (lane == 0) {
    double mx = acc[0];
    for (int e = 1; e < NEXP; e++) mx = fmax(mx, acc[e]);
    double p[NEXP], sum = 0.0;
    for (int e = 0; e < NEXP; e++) { p[e] = exp(acc[e] - mx); sum += p[e]; }
    for (int e = 0; e < NEXP; e++) p[e] /= sum;
    int i0 = 0;
    for (int e = 1; e < NEXP; e++) if (p[e] > p[i0]) i0 = e;
    int i1 = (i0 == 0) ? 1 : 0;
    for (int e = 0; e < NEXP; e++) if (e != i0 && p[e] > p[i1]) i1 = e;
    int pos0 = atomicAdd(&cnt[i0], 1);
    tmp_tok[i0 * M_TOK + pos0] = tok;
    int pos1 = atomicAdd(&cnt[i1], 1);
    tmp_tok[i1 * M_TOK + pos1] = tok;
    rec_i[tok] = make_int4(i0, pos0, i1, pos1);
    rec_g[tok] = make_float2((float)p[i0], (float)p[i1]);
  }
}

// ---------- 2: offsets (pad to 128), tile list, compact ----------
__global__ void finalize_kernel(const int* __restrict__ cnt, int* __restrict__ pofs,
                                int* __restrict__ meta, int* __restrict__ tle,
                                int* __restrict__ tlr, int* __restrict__ ptok,
                                const int* __restrict__ tmp_tok) {
  __shared__ int ofs[NEXP];
  if (threadIdx.x == 0) {
    int o = 0, t = 0;
    for (int e = 0; e < NEXP; e++) {
      ofs[e] = o; pofs[e] = o;
      int nt = (cnt[e] + 127) >> 7;
      for (int i = 0; i < nt; i++) { tle[t] = e; tlr[t] = o + i * 128; t++; }
      o += nt << 7;
    }
    meta[0] = o; meta[1] = t;
  }
  __syncthreads();
  for (int i = threadIdx.x; i < NEXP * M_TOK; i += 256) {
    int e = i >> 11, sl = i & 2047;
    int c = cnt[e];
    int padded = ((c + 127) >> 7) << 7;
    if (sl < padded) {
      int dst = ofs[e] + sl;
      ptok[dst] = (sl < c) ? tmp_tok[i] : -1;
    }
  }
}

// ---------- 3: gather x rows -> bf16 Xg ----------
__global__ void gather_kernel(const float* __restrict__ x, const int* __restrict__ ptok,
                              const int* __restrict__ meta, ushort_t* __restrict__ Xg) {
  int r = blockIdx.x;
  if (r >= meta[0]) return;
  int tok = ptok[r];
  int t = threadIdx.x;
  ushort4 b;
  if (tok >= 0) {
    float4 v = *(const float4*)(x + (size_t)tok * DDIM + t * 4);
    b.x = f2b(v.x); b.y = f2b(v.y); b.z = f2b(v.z); b.w = f2b(v.w);
  } else {
    b.x = 0; b.y = 0; b.z = 0; b.w = 0;
  }
  *(ushort4*)(Xg + (size_t)r * DDIM + t * 4) = b;
}

// ---------- 4: GEMM1 — depth-2 counted-vmcnt pipeline, tiled-B addressing ----------
__launch_bounds__(256, 2)
__global__ void gemm1_kernel(const ushort_t* __restrict__ Xg,
                             const ushort_t* __restrict__ WvT, const ushort_t* __restrict__ WT,
                             const int* __restrict__ tle, const int* __restrict__ tlr,
                             const int* __restrict__ meta, ushort_t* __restrict__ G) {
  int b = blockIdx.x;                              // 1280 = 8*160
  int bid = (b & 7) * 160 + (b >> 3);              // bijective XCD chunk swizzle
  int ct = bid / NTMAX;
  int t  = bid - ct * NTMAX;
  if (t >= meta[1]) return;
  int e = tle[t], gr0 = tlr[t];

  __shared__ ushort_t As0[128][32], Bv0[128][32], Bw0[128][32];
  __shared__ ushort_t As1[128][32], Bv1[128][32], Bw1[128][32];

  int tid = threadIdx.x, wid = tid >> 6, lane = tid & 63;
  int wr = wid >> 1, wc = wid & 1;
  int srow = wid * 32 + (lane >> 2);
  int scol = (lane & 3) * 8;

  const ushort_t* Ap  = Xg + (size_t)(gr0 + srow) * DDIM + scol;
  // tiled layout: W'[e][k/128][n:4096][128]
  const ushort_t* Bvp = WvT + ((size_t)(e * 8) * FDIM + ct * 128 + srow) * 128 + scol;
  const ushort_t* Bwp = WT  + ((size_t)(e * 8) * FDIM + ct * 128 + srow) * 128 + scol;
#define BOFF1(kk) ((size_t)((kk) >> 2) * (FDIM * 128) + ((kk) & 3) * 32)

  f32x4 accv[4][4], accy[4][4];
  f32x4 zf = {0.f, 0.f, 0.f, 0.f};
#pragma unroll
  for (int mi = 0; mi < 4; mi++)
#pragma unroll
    for (int ni = 0; ni < 4; ni++) { accv[mi][ni] = zf; accy[mi][ni] = zf; }

  short8 af[4], bvf[4], bwf[4];

#define STG1(As_, Bv_, Bw_, kk) do {                                             \
    gload_lds16(Ap  + (kk) * 32,             &As_[wid * 32][0]);                 \
    gload_lds16(Ap  + (kk) * 32 + 16 * DDIM, &As_[wid * 32 + 16][0]);            \
    gload_lds16(Bvp + BOFF1(kk),             &Bv_[wid * 32][0]);                 \
    gload_lds16(Bvp + BOFF1(kk) + 2048,      &Bv_[wid * 32 + 16][0]);            \
    gload_lds16(Bwp + BOFF1(kk),             &Bw_[wid * 32][0]);                 \
    gload_lds16(Bwp + BOFF1(kk) + 2048,      &Bw_[wid * 32 + 16][0]);            \
  } while (0)

#define RD1(As_, Bv_, Bw_) do {                                                  \
    _Pragma("unroll") for (int mi = 0; mi < 4; mi++)                             \
      af[mi] = *(const short8*)&As_[wr*64 + mi*16 + (lane&15)][(lane>>4)*8];     \
    _Pragma("unroll") for (int ni = 0; ni < 4; ni++) {                           \
      bvf[ni] = *(const short8*)&Bv_[wc*64 + ni*16 + (lane&15)][(lane>>4)*8];    \
      bwf[ni] = *(const short8*)&Bw_[wc*64 + ni*16 + (lane&15)][(lane>>4)*8]; }  \
  } while (0)

#define MM1() do {                                                               \
    _Pragma("unroll") for (int mi = 0; mi < 4; mi++)                             \
      _Pragma("unroll") for (int ni = 0; ni < 4; ni++) {                         \
        accv[mi][ni] = __builtin_amdgcn_mfma_f32_16x16x32_bf16(af[mi], bvf[ni], accv[mi][ni], 0, 0, 0); \
        accy[mi][ni] = __builtin_amdgcn_mfma_f32_16x16x32_bf16(af[mi], bwf[ni], accy[mi][ni], 0, 0, 0); } \
  } while (0)

  STG1(As0, Bv0, Bw0, 0);
  STG1(As1, Bv1, Bw1, 1);

  for (int kt = 0; kt < 30; kt += 2) {
    asm volatile("s_waitcnt vmcnt(6)" ::: "memory");
    __builtin_amdgcn_sched_barrier(0);
    __builtin_amdgcn_s_barrier();
    RD1(As0, Bv0, Bw0);
    asm volatile("s_waitcnt lgkmcnt(0)" ::: "memory");
    __builtin_amdgcn_sched_barrier(0);
    __builtin_amdgcn_s_barrier();
    STG1(As0, Bv0, Bw0, kt + 2);
    MM1();
    asm volatile("s_waitcnt vmcnt(6)" ::: "memory");
    __builtin_amdgcn_sched_barrier(0);
    __builtin_amdgcn_s_barrier();
    RD1(As1, Bv1, Bw1);
    asm volatile("s_waitcnt lgkmcnt(0)" ::: "memory");
    __builtin_amdgcn_sched_barrier(0);
    __builtin_amdgcn_s_barrier();
    STG1(As1, Bv1, Bw1, kt + 3);
    MM1();
  }
  asm volatile("s_waitcnt vmcnt(6)" ::: "memory");
  __builtin_amdgcn_sched_barrier(0);
  __builtin_amdgcn_s_barrier();
  RD1(As0, Bv0, Bw0);
  MM1();
  asm volatile("s_waitcnt vmcnt(0)" ::: "memory");
  __builtin_amdgcn_sched_barrier(0);
  __builtin_amdgcn_s_barrier();
  RD1(As1, Bv1, Bw1);
  MM1();
#undef STG1
#undef RD1
#undef MM1

#pragma unroll
  for (int ni = 0; ni < 4; ni++) {
    int coll = wc * 64 + ni * 16 + (lane & 15);
#pragma unroll
    for (int mi = 0; mi < 4; mi++)
#pragma unroll
      for (int q = 0; q < 4; q++) {
        int rowl = wr * 64 + mi * 16 + (lane >> 4) * 4 + q;
        float g = accv[mi][ni][q] * gelu_tanh(accy[mi][ni][q]);
        G[(size_t)(gr0 + rowl) * FDIM + ct * 128 + coll] = f2b(g);
      }
  }
}

// ---------- 5: GEMM2 — depth-2 counted-vmcnt, K-split x2, tiled-B, P0/P1 stores ----------
__launch_bounds__(256, 3)
__global__ void gemm2_kernel(const ushort_t* __restrict__ G,
                             const ushort_t* __restrict__ W1T,
                             const int* __restrict__ tle, const int* __restrict__ tlr,
                             const int* __restrict__ meta,
                             float* __restrict__ P0, float* __restrict__ P1) {
  int b = blockIdx.x;                              // 640 = 8*80
  int bid = (b & 7) * 80 + (b >> 3);
  int grp = bid / NTMAX;                           // 0..15 = ct*2+ks
  int t = bid - grp * NTMAX;
  if (t >= meta[1]) return;
  int ct = grp >> 1, ks = grp & 1;
  int e = tle[t], gr0 = tlr[t];
  int k0 = ks * (FDIM / 2);
  float* P = ks ? P1 : P0;

  __shared__ ushort_t As0[128][32], Bs0[128][32];
  __shared__ ushort_t As1[128][32], Bs1[128][32];

  int tid = threadIdx.x, wid = tid >> 6, lane = tid & 63;
  int wr = wid >> 1, wc = wid & 1;
  int srow = wid * 32 + (lane >> 2);
  int scol = (lane & 3) * 8;

  const ushort_t* Ap = G + (size_t)(gr0 + srow) * FDIM + k0 + scol;
  // tiled layout: W1'[e][k/128: 32][n:1024][128]; ks half starts at ktile e*32+ks*16
  const ushort_t* Bp = W1T + ((size_t)(e * 32 + ks * 16) * DDIM + ct * 128 + srow) * 128 + scol;
#define BOFF2(kk) ((size_t)((kk) >> 2) * (DDIM * 128) + ((kk) & 3) * 32)

  f32x4 acc[4][4];
  f32x4 zf = {0.f, 0.f, 0.f, 0.f};
#pragma unroll
  for (int mi = 0; mi < 4; mi++)
#pragma unroll
    for (int ni = 0; ni < 4; ni++) acc[mi][ni] = zf;

  short8 af[4], bf[4];

#define STG2(As_, Bs_, kk) do {                                                  \
    gload_lds16(Ap + (kk) * 32,             &As_[wid * 32][0]);                  \
    gload_lds16(Ap + (kk) * 32 + 16 * FDIM, &As_[wid * 32 + 16][0]);             \
    gload_lds16(Bp + BOFF2(kk),             &Bs_[wid * 32][0]);                  \
    gload_lds16(Bp + BOFF2(kk) + 2048,      &Bs_[wid * 32 + 16][0]);             \
  } while (0)

#define RD2(As_, Bs_) do {                                                       \
    _Pragma("unroll") for (int mi = 0; mi < 4; mi++)                             \
      af[mi] = *(const short8*)&As_[wr*64 + mi*16 + (lane&15)][(lane>>4)*8];     \
    _Pragma("unroll") for (int ni = 0; ni < 4; ni++)                             \
      bf[ni] = *(const short8*)&Bs_[wc*64 + ni*16 + (lane&15)][(lane>>4)*8];     \
  } while (0)

#define MM2() do {                                                               \
    _Pragma("unroll") for (int mi = 0; mi < 4; mi++)                             \
      _Pragma("unroll") for (int ni = 0; ni < 4; ni++)                           \
        acc[mi][ni] = __builtin_amdgcn_mfma_f32_16x16x32_bf16(af[mi], bf[ni], acc[mi][ni], 0, 0, 0); \
  } while (0)

  STG2(As0, Bs0, 0);
  STG2(As1, Bs1, 1);

  for (int kt = 0; kt < 62; kt += 2) {
    asm volatile("s_waitcnt vmcnt(4)" ::: "memory");
    __builtin_amdgcn_sched_barrier(0);
    __builtin_amdgcn_s_barrier();
    RD2(As0, Bs0);
    asm volatile("s_waitcnt lgkmcnt(0)" ::: "memory");
    __builtin_amdgcn_sched_barrier(0);
    __builtin_amdgcn_s_barrier();
    STG2(As0, Bs0, kt + 2);
    MM2();
    asm volatile("s_waitcnt vmcnt(4)" ::: "memory");
    __builtin_amdgcn_sched_barrier(0);
    __builtin_amdgcn_s_barrier();
    RD2(As1, Bs1);
    asm volatile("s_waitcnt lgkmcnt(0)" ::: "memory");
    __builtin_amdgcn_sched_barrier(0);
    __builtin_amdgcn_s_barrier();
    STG2(As1, Bs1, kt + 3);
    MM2();
  }
  asm volatile("s_waitcnt vmcnt(4)" ::: "memory");
  __builtin_amdgcn_sched_barrier(0);
  __builtin_amdgcn_s_barrier();
  RD2(As0, Bs0);
  MM2();
  asm volatile("s_waitcnt vmcnt(0)" ::: "memory");
  __builtin_amdgcn_sched_barrier(0);
  __builtin_amdgcn_s_barrier();
  RD2(As1, Bs1);
  MM2();
#undef STG2
#undef RD2
#undef MM2

#pragma unroll
  for (int ni = 0; ni < 4; ni++) {
    int coll = wc * 64 + ni * 16 + (lane & 15);
#pragma unroll
    for (int mi = 0; mi < 4; mi++)
#pragma unroll
      for (int q = 0; q < 4; q++) {
        int rowl = wr * 64 + mi * 16 + (lane >> 4) * 4 + q;
        P[(size_t)(gr0 + rowl) * DDIM + ct * 128 + coll] = acc[mi][ni][q];
      }
  }
}

// ---------- 6: combine: out[tok] = g0*(P0+P1)[row0] + g1*(P0+P1)[row1] ----------
__global__ void combine_kernel(const float* __restrict__ P0, const float* __restrict__ P1,
                               const int4* __restrict__ rec_i, const float2* __restrict__ rec_g,
                               const int* __restrict__ pofs, float* __restrict__ out) {
  int tok = blockIdx.x;
  int c = threadIdx.x * 4;
  int4 ri = rec_i[tok];
  float2 rg = rec_g[tok];
  size_t r0 = (size_t)(pofs[ri.x] + ri.y) * DDIM + c;
  size_t r1 = (size_t)(pofs[ri.z] + ri.w) * DDIM + c;
  float4 a0 = *(const float4*)(P0 + r0);
  float4 b0 = *(const float4*)(P1 + r0);
  float4 a1 = *(const float4*)(P0 + r1);
  float4 b1 = *(const float4*)(P1 + r1);
  float4 o;
  o.x = rg.x * (a0.x + b0.x) + rg.y * (a1.x + b1.x);
  o.y = rg.x * (a0.y + b0.y) + rg.y * (a1.y + b1.y);
  o.z = rg.x * (a0.z + b0.z) + rg.y * (a1.z + b1.z);
  o.w = rg.x * (a0.w + b0.w) + rg.y * (a1.w + b1.w);
  *(float4*)(out + (size_t)tok * DDIM + c) = o;
}

// ---------- launch ----------
extern "C" void kernel_launch(void* const* d_in, const int* in_sizes, int n_in,
                              void* d_out, int out_size, void* d_ws, size_t ws_size,
                              hipStream_t stream) {
  const float* x  = (const float*)d_in[0];
  const float* rw = (const float*)d_in[1];
  const float* wv = (const float*)d_in[2];
  const float* sv = (const float*)d_in[3];
  const float* w  = (const float*)d_in[4];
  const float* s  = (const float*)d_in[5];
  const float* w1 = (const float*)d_in[6];
  const float* s1 = (const float*)d_in[7];
  float* out = (float*)d_out;

  char* ws = (char*)d_ws;
  int*    cnt      = (int*)(ws + 0);
  int*    pofs     = (int*)(ws + 64);
  int*    meta     = (int*)(ws + 128);
  int*    tle      = (int*)(ws + 192);
  int*    tlr      = (int*)(ws + 1024);
  int*    tmp_tok  = (int*)(ws + 2048);
  int*    ptok     = (int*)(ws + 133120);
  int4*   rec_i    = (int4*)(ws + 174080);
  float2* rec_g    = (float2*)(ws + 206848);
  ushort_t* Xg     = (ushort_t*)(ws + 223232);       // 10 MB
  ushort_t* G      = (ushort_t*)(ws + 10708992);     // 40 MB
  ushort_t* WvT    = (ushort_t*)(ws + 52652032);     // 64 MB (dead after gemm1)
  ushort_t* WT     = (ushort_t*)(ws + 119760896);    // 64 MB
  ushort_t* W1T    = (ushort_t*)(ws + 186869760);    // 64 MB (end ~242 MB)
  float*  P0       = (float*)(ws + 52652032);        // overlay old WvT (20 MB)
  float*  P1       = (float*)(ws + 73623552);        // overlay old WvT (20 MB)

  hipMemsetAsync(cnt, 0, NEXP * sizeof(int), stream);
  conv_router_kernel<<<12800, 256, 0, stream>>>(wv, sv, w, s, w1, s1, WvT, WT, W1T,
                                                x, rw, cnt, tmp_tok, rec_i, rec_g);
  finalize_kernel<<<1, 256, 0, stream>>>(cnt, pofs, meta, tle, tlr, ptok, tmp_tok);
  gather_kernel<<<5120, 256, 0, stream>>>(x, ptok, meta, Xg);
  gemm1_kernel<<<1280, 256, 0, stream>>>(Xg, WvT, WT, tle, tlr, meta, G);
  gemm2_kernel<<<640, 256, 0, stream>>>(G, W1T, tle, tlr, meta, P0, P1);
  combine_kernel<<<2048, 256, 0, stream>>>(P0, P1, rec_i, rec_g, pofs, out);
}

// Round 14
// 368.894 us; speedup vs baseline: 1.5187x; 1.0010x over previous
//
#include <hip/hip_runtime.h>
#include <hip/hip_bf16.h>
#include <math.h>

#define M_TOK 2048
#define DDIM  1024
#define FDIM  4096
#define NEXP  8
#define TOTROWS 5120
#define NTMAX 40

typedef __attribute__((ext_vector_type(8))) short short8;
typedef __attribute__((ext_vector_type(4))) float f32x4;
typedef unsigned short ushort_t;

// ---------- helpers ----------
__device__ inline unsigned short f2b(float f) {        // f32 -> bf16 RNE
  unsigned int u = __float_as_uint(f);
  u = u + 0x7FFFu + ((u >> 16) & 1u);
  return (unsigned short)(u >> 16);
}

__device__ inline float gelu_tanh(float u) {           // jax.nn.gelu approximate=True
  float u3 = u * u * u;
  float a  = 0.7978845608028654f * (u + 0.044715f * u3);
  float e  = __expf(2.0f * a);
  float t  = 1.0f - 2.0f / (e + 1.0f);                 // tanh(a), inf-safe
  return 0.5f * u * (1.0f + t);
}

__device__ inline void gload_lds16(const void* g, void* l) {
  __builtin_amdgcn_global_load_lds(
      (const __attribute__((address_space(1))) unsigned int*)g,
      (__attribute__((address_space(3))) unsigned int*)l, 16, 0, 0);
}

__device__ inline float fget(const float4& v, int j) {
  return j == 0 ? v.x : j == 1 ? v.y : j == 2 ? v.z : v.w;
}

// ---------- convert core: 128k x 64n half-tile -> TILED dst [e][K/128][N][128] ----------
// All 8 global loads issued BEFORE any use (sched_barrier fence forces MLP=8).
__device__ inline void convert_half(const float* __restrict__ src, const float* __restrict__ scale,
                                    ushort_t* __restrict__ dst, int K, int N, int e, int tk, int n0,
                                    unsigned int* L, int t) {
  const float* S  = src + (size_t)e * K * N + (size_t)(tk * 128) * N + n0;
  ushort_t*    Dt = dst + ((size_t)(e * (K >> 7) + tk) * N + n0) * 128;
  const float* sc = scale + (size_t)e * N + n0;
  int lg = t >> 4, ll = t & 15;
  int c0 = ll * 4;
  float4 scv = *(const float4*)(sc + c0);

  float4 v0[4], v1[4];                     // 8 loads in flight (32 VGPR)
#pragma unroll
  for (int i = 0; i < 4; i++) {
    int r = (i * 16 + lg) * 2;
    v0[i] = *(const float4*)(S + (size_t)r * N + c0);
    v1[i] = *(const float4*)(S + (size_t)(r + 1) * N + c0);
  }
  __builtin_amdgcn_sched_barrier(0);       // fence: no use hoisted above, no load sunk below
#pragma unroll
  for (int i = 0; i < 4; i++) {
    int p = i * 16 + lg;                   // pair-row 0..63
#pragma unroll
    for (int j = 0; j < 4; j++) {
      unsigned int pk = (unsigned int)f2b(fget(v0[i], j) * fget(scv, j))
                      | ((unsigned int)f2b(fget(v1[i], j) * fget(scv, j)) << 16);
      L[(c0 + j) * 65 + p] = pk;           // bank = (4ll+j+16i+lg)%32: 2-way, free
    }
  }
  __syncthreads();
#pragma unroll
  for (int q = 0; q < 4; q++) {
    int nl = q * 16 + lg;                  // 0..63
    int kc = ll * 8;                       // 0..120
    unsigned int* base = &L[nl * 65 + (kc >> 1)];
    uint4 o;
    o.x = base[0]; o.y = base[1]; o.z = base[2]; o.w = base[3];
    *(uint4*)(Dt + (size_t)nl * 128 + kc) = o;   // contiguous 256B/row, 16KB/block
  }
}

// ---------- K_A: convert(wv,w,w1) 12288 half-blocks || router 512 blocks ----------
__launch_bounds__(256, 4)
__global__ void conv_router_kernel(const float* __restrict__ wv, const float* __restrict__ sv,
                                   const float* __restrict__ w,  const float* __restrict__ s,
                                   const float* __restrict__ w1, const float* __restrict__ s1,
                                   ushort_t* __restrict__ WvT, ushort_t* __restrict__ WT,
                                   ushort_t* __restrict__ W1T,
                                   const float* __restrict__ x, const float* __restrict__ rw,
                                   int* __restrict__ cnt, int* __restrict__ tmp_tok,
                                   int4* __restrict__ rec_i, float2* __restrict__ rec_g) {
  __shared__ unsigned int L[64 * 65];
  int b = blockIdx.x;
  if (b < 12288) {
    int z = b >> 12;                        // 0: wv, 1: w, 2: w1
    int bb = b & 4095;
    int e = bb >> 9, rem = bb & 511;
    if (z == 2) {
      int tk = rem >> 4, n0 = (rem & 15) * 64;          // K=4096: 32 ktiles; N=1024: 16 slabs
      convert_half(w1, s1, W1T, FDIM, DDIM, e, tk, n0, L, threadIdx.x);
    } else {
      int tk = rem >> 6, n0 = (rem & 63) * 64;          // K=1024: 8 ktiles; N=4096: 64 slabs
      convert_half(z ? w : wv, z ? s : sv, z ? WT : WvT, DDIM, FDIM, e, tk, n0, L, threadIdx.x);
    }
    return;
  }
  // ---- router path ----
  int tok  = (b - 12288) * 4 + (threadIdx.x >> 6);
  int lane = threadIdx.x & 63;
  const float* xr = x + (size_t)tok * DDIM;
  double acc[NEXP];
#pragma unroll
  for (int e = 0; e < NEXP; e++) acc[e] = 0.0;
  for (int d = lane; d < DDIM; d += 64) {
    double xv = (double)xr[d];
    const float* rp = rw + (size_t)d * NEXP;
#pragma unroll
    for (int e = 0; e < NEXP; e++) acc[e] += xv * (double)rp[e];
  }
#pragma unroll
  for (int off = 32; off >= 1; off >>= 1) {
#pragma unroll
    for (int e = 0; e < NEXP; e++) acc[e] += __shfl_down(acc[e], off, 64);
  }
  if (lane == 0) {
    double mx = acc[0];
    for (int e = 1; e < NEXP; e++) mx = fmax(mx, acc[e]);
    double p[NEXP], sum = 0.0;
    for (int e = 0; e < NEXP; e++) { p[e] = exp(acc[e] - mx); sum += p[e]; }
    for (int e = 0; e < NEXP; e++) p[e] /= sum;
    int i0 = 0;
    for (int e = 1; e < NEXP; e++) if (p[e] > p[i0]) i0 = e;
    int i1 = (i0 == 0) ? 1 : 0;
    for (int e = 0; e < NEXP; e++) if (e != i0 && p[e] > p[i1]) i1 = e;
    int pos0 = atomicAdd(&cnt[i0], 1);
    tmp_tok[i0 * M_TOK + pos0] = tok;
    int pos1 = atomicAdd(&cnt[i1], 1);
    tmp_tok[i1 * M_TOK + pos1] = tok;
    rec_i[tok] = make_int4(i0, pos0, i1, pos1);
    rec_g[tok] = make_float2((float)p[i0], (float)p[i1]);
  }
}

// ---------- 2: offsets (pad to 128), tile list, compact ----------
__global__ void finalize_kernel(const int* __restrict__ cnt, int* __restrict__ pofs,
                                int* __restrict__ meta, int* __restrict__ tle,
                                int* __restrict__ tlr, int* __restrict__ ptok,
                                const int* __restrict__ tmp_tok) {
  __shared__ int ofs[NEXP];
  if (threadIdx.x == 0) {
    int o = 0, t = 0;
    for (int e = 0; e < NEXP; e++) {
      ofs[e] = o; pofs[e] = o;
      int nt = (cnt[e] + 127) >> 7;
      for (int i = 0; i < nt; i++) { tle[t] = e; tlr[t] = o + i * 128; t++; }
      o += nt << 7;
    }
    meta[0] = o; meta[1] = t;
  }
  __syncthreads();
  for (int i = threadIdx.x; i < NEXP * M_TOK; i += 256) {
    int e = i >> 11, sl = i & 2047;
    int c = cnt[e];
    int padded = ((c + 127) >> 7) << 7;
    if (sl < padded) {
      int dst = ofs[e] + sl;
      ptok[dst] = (sl < c) ? tmp_tok[i] : -1;
    }
  }
}

// ---------- 3: gather x rows -> bf16 Xg ----------
__global__ void gather_kernel(const float* __restrict__ x, const int* __restrict__ ptok,
                              const int* __restrict__ meta, ushort_t* __restrict__ Xg) {
  int r = blockIdx.x;
  if (r >= meta[0]) return;
  int tok = ptok[r];
  int t = threadIdx.x;
  ushort4 b;
  if (tok >= 0) {
    float4 v = *(const float4*)(x + (size_t)tok * DDIM + t * 4);
    b.x = f2b(v.x); b.y = f2b(v.y); b.z = f2b(v.z); b.w = f2b(v.w);
  } else {
    b.x = 0; b.y = 0; b.z = 0; b.w = 0;
  }
  *(ushort4*)(Xg + (size_t)r * DDIM + t * 4) = b;
}

// ---------- 4: GEMM1 — depth-2 counted-vmcnt pipeline, tiled-B addressing ----------
__launch_bounds__(256, 2)
__global__ void gemm1_kernel(const ushort_t* __restrict__ Xg,
                             const ushort_t* __restrict__ WvT, const ushort_t* __restrict__ WT,
                             const int* __restrict__ tle, const int* __restrict__ tlr,
                             const int* __restrict__ meta, ushort_t* __restrict__ G) {
  int b = blockIdx.x;                              // 1280 = 8*160
  int bid = (b & 7) * 160 + (b >> 3);              // bijective XCD chunk swizzle
  int ct = bid / NTMAX;
  int t  = bid - ct * NTMAX;
  if (t >= meta[1]) return;
  int e = tle[t], gr0 = tlr[t];

  __shared__ ushort_t As0[128][32], Bv0[128][32], Bw0[128][32];
  __shared__ ushort_t As1[128][32], Bv1[128][32], Bw1[128][32];

  int tid = threadIdx.x, wid = tid >> 6, lane = tid & 63;
  int wr = wid >> 1, wc = wid & 1;
  int srow = wid * 32 + (lane >> 2);
  int scol = (lane & 3) * 8;

  const ushort_t* Ap  = Xg + (size_t)(gr0 + srow) * DDIM + scol;
  // tiled layout: W'[e][k/128][n:4096][128]
  const ushort_t* Bvp = WvT + ((size_t)(e * 8) * FDIM + ct * 128 + srow) * 128 + scol;
  const ushort_t* Bwp = WT  + ((size_t)(e * 8) * FDIM + ct * 128 + srow) * 128 + scol;
#define BOFF1(kk) ((size_t)((kk) >> 2) * (FDIM * 128) + ((kk) & 3) * 32)

  f32x4 accv[4][4], accy[4][4];
  f32x4 zf = {0.f, 0.f, 0.f, 0.f};
#pragma unroll
  for (int mi = 0; mi < 4; mi++)
#pragma unroll
    for (int ni = 0; ni < 4; ni++) { accv[mi][ni] = zf; accy[mi][ni] = zf; }

  short8 af[4], bvf[4], bwf[4];

#define STG1(As_, Bv_, Bw_, kk) do {                                             \
    gload_lds16(Ap  + (kk) * 32,             &As_[wid * 32][0]);                 \
    gload_lds16(Ap  + (kk) * 32 + 16 * DDIM, &As_[wid * 32 + 16][0]);            \
    gload_lds16(Bvp + BOFF1(kk),             &Bv_[wid * 32][0]);                 \
    gload_lds16(Bvp + BOFF1(kk) + 2048,      &Bv_[wid * 32 + 16][0]);            \
    gload_lds16(Bwp + BOFF1(kk),             &Bw_[wid * 32][0]);                 \
    gload_lds16(Bwp + BOFF1(kk) + 2048,      &Bw_[wid * 32 + 16][0]);            \
  } while (0)

#define RD1(As_, Bv_, Bw_) do {                                                  \
    _Pragma("unroll") for (int mi = 0; mi < 4; mi++)                             \
      af[mi] = *(const short8*)&As_[wr*64 + mi*16 + (lane&15)][(lane>>4)*8];     \
    _Pragma("unroll") for (int ni = 0; ni < 4; ni++) {                           \
      bvf[ni] = *(const short8*)&Bv_[wc*64 + ni*16 + (lane&15)][(lane>>4)*8];    \
      bwf[ni] = *(const short8*)&Bw_[wc*64 + ni*16 + (lane&15)][(lane>>4)*8]; }  \
  } while (0)

#define MM1() do {                                                               \
    _Pragma("unroll") for (int mi = 0; mi < 4; mi++)                             \
      _Pragma("unroll") for (int ni = 0; ni < 4; ni++) {                         \
        accv[mi][ni] = __builtin_amdgcn_mfma_f32_16x16x32_bf16(af[mi], bvf[ni], accv[mi][ni], 0, 0, 0); \
        accy[mi][ni] = __builtin_amdgcn_mfma_f32_16x16x32_bf16(af[mi], bwf[ni], accy[mi][ni], 0, 0, 0); } \
  } while (0)

  STG1(As0, Bv0, Bw0, 0);
  STG1(As1, Bv1, Bw1, 1);

  for (int kt = 0; kt < 30; kt += 2) {
    asm volatile("s_waitcnt vmcnt(6)" ::: "memory");
    __builtin_amdgcn_sched_barrier(0);
    __builtin_amdgcn_s_barrier();
    RD1(As0, Bv0, Bw0);
    asm volatile("s_waitcnt lgkmcnt(0)" ::: "memory");
    __builtin_amdgcn_sched_barrier(0);
    __builtin_amdgcn_s_barrier();
    STG1(As0, Bv0, Bw0, kt + 2);
    MM1();
    asm volatile("s_waitcnt vmcnt(6)" ::: "memory");
    __builtin_amdgcn_sched_barrier(0);
    __builtin_amdgcn_s_barrier();
    RD1(As1, Bv1, Bw1);
    asm volatile("s_waitcnt lgkmcnt(0)" ::: "memory");
    __builtin_amdgcn_sched_barrier(0);
    __builtin_amdgcn_s_barrier();
    STG1(As1, Bv1, Bw1, kt + 3);
    MM1();
  }
  asm volatile("s_waitcnt vmcnt(6)" ::: "memory");
  __builtin_amdgcn_sched_barrier(0);
  __builtin_amdgcn_s_barrier();
  RD1(As0, Bv0, Bw0);
  MM1();
  asm volatile("s_waitcnt vmcnt(0)" ::: "memory");
  __builtin_amdgcn_sched_barrier(0);
  __builtin_amdgcn_s_barrier();
  RD1(As1, Bv1, Bw1);
  MM1();
#undef STG1
#undef RD1
#undef MM1

#pragma unroll
  for (int ni = 0; ni < 4; ni++) {
    int coll = wc * 64 + ni * 16 + (lane & 15);
#pragma unroll
    for (int mi = 0; mi < 4; mi++)
#pragma unroll
      for (int q = 0; q < 4; q++) {
        int rowl = wr * 64 + mi * 16 + (lane >> 4) * 4 + q;
        float g = accv[mi][ni][q] * gelu_tanh(accy[mi][ni][q]);
        G[(size_t)(gr0 + rowl) * FDIM + ct * 128 + coll] = f2b(g);
      }
  }
}

// ---------- 5: GEMM2 — depth-2 counted-vmcnt, K-split x2, tiled-B, P0/P1 stores ----------
__launch_bounds__(256, 3)
__global__ void gemm2_kernel(const ushort_t* __restrict__ G,
                             const ushort_t* __restrict__ W1T,
                             const int* __restrict__ tle, const int* __restrict__ tlr,
                             const int* __restrict__ meta,
                             float* __restrict__ P0, float* __restrict__ P1) {
  int b = blockIdx.x;                              // 640 = 8*80
  int bid = (b & 7) * 80 + (b >> 3);
  int grp = bid / NTMAX;                           // 0..15 = ct*2+ks
  int t = bid - grp * NTMAX;
  if (t >= meta[1]) return;
  int ct = grp >> 1, ks = grp & 1;
  int e = tle[t], gr0 = tlr[t];
  int k0 = ks * (FDIM / 2);
  float* P = ks ? P1 : P0;

  __shared__ ushort_t As0[128][32], Bs0[128][32];
  __shared__ ushort_t As1[128][32], Bs1[128][32];

  int tid = threadIdx.x, wid = tid >> 6, lane = tid & 63;
  int wr = wid >> 1, wc = wid & 1;
  int srow = wid * 32 + (lane >> 2);
  int scol = (lane & 3) * 8;

  const ushort_t* Ap = G + (size_t)(gr0 + srow) * FDIM + k0 + scol;
  // tiled layout: W1'[e][k/128: 32][n:1024][128]; ks half starts at ktile e*32+ks*16
  const ushort_t* Bp = W1T + ((size_t)(e * 32 + ks * 16) * DDIM + ct * 128 + srow) * 128 + scol;
#define BOFF2(kk) ((size_t)((kk) >> 2) * (DDIM * 128) + ((kk) & 3) * 32)

  f32x4 acc[4][4];
  f32x4 zf = {0.f, 0.f, 0.f, 0.f};
#pragma unroll
  for (int mi = 0; mi < 4; mi++)
#pragma unroll
    for (int ni = 0; ni < 4; ni++) acc[mi][ni] = zf;

  short8 af[4], bf[4];

#define STG2(As_, Bs_, kk) do {                                                  \
    gload_lds16(Ap + (kk) * 32,             &As_[wid * 32][0]);                  \
    gload_lds16(Ap + (kk) * 32 + 16 * FDIM, &As_[wid * 32 + 16][0]);             \
    gload_lds16(Bp + BOFF2(kk),             &Bs_[wid * 32][0]);                  \
    gload_lds16(Bp + BOFF2(kk) + 2048,      &Bs_[wid * 32 + 16][0]);             \
  } while (0)

#define RD2(As_, Bs_) do {                                                       \
    _Pragma("unroll") for (int mi = 0; mi < 4; mi++)                             \
      af[mi] = *(const short8*)&As_[wr*64 + mi*16 + (lane&15)][(lane>>4)*8];     \
    _Pragma("unroll") for (int ni = 0; ni < 4; ni++)                             \
      bf[ni] = *(const short8*)&Bs_[wc*64 + ni*16 + (lane&15)][(lane>>4)*8];     \
  } while (0)

#define MM2() do {                                                               \
    _Pragma("unroll") for (int mi = 0; mi < 4; mi++)                             \
      _Pragma("unroll") for (int ni = 0; ni < 4; ni++)                           \
        acc[mi][ni] = __builtin_amdgcn_mfma_f32_16x16x32_bf16(af[mi], bf[ni], acc[mi][ni], 0, 0, 0); \
  } while (0)

  STG2(As0, Bs0, 0);
  STG2(As1, Bs1, 1);

  for (int kt = 0; kt < 62; kt += 2) {
    asm volatile("s_waitcnt vmcnt(4)" ::: "memory");
    __builtin_amdgcn_sched_barrier(0);
    __builtin_amdgcn_s_barrier();
    RD2(As0, Bs0);
    asm volatile("s_waitcnt lgkmcnt(0)" ::: "memory");
    __builtin_amdgcn_sched_barrier(0);
    __builtin_amdgcn_s_barrier();
    STG2(As0, Bs0, kt + 2);
    MM2();
    asm volatile("s_waitcnt vmcnt(4)" ::: "memory");
    __builtin_amdgcn_sched_barrier(0);
    __builtin_amdgcn_s_barrier();
    RD2(As1, Bs1);
    asm volatile("s_waitcnt lgkmcnt(0)" ::: "memory");
    __builtin_amdgcn_sched_barrier(0);
    __builtin_amdgcn_s_barrier();
    STG2(As1, Bs1, kt + 3);
    MM2();
  }
  asm volatile("s_waitcnt vmcnt(4)" ::: "memory");
  __builtin_amdgcn_sched_barrier(0);
  __builtin_amdgcn_s_barrier();
  RD2(As0, Bs0);
  MM2();
  asm volatile("s_waitcnt vmcnt(0)" ::: "memory");
  __builtin_amdgcn_sched_barrier(0);
  __builtin_amdgcn_s_barrier();
  RD2(As1, Bs1);
  MM2();
#undef STG2
#undef RD2
#undef MM2

#pragma unroll
  for (int ni = 0; ni < 4; ni++) {
    int coll = wc * 64 + ni * 16 + (lane & 15);
#pragma unroll
    for (int mi = 0; mi < 4; mi++)
#pragma unroll
      for (int q = 0; q < 4; q++) {
        int rowl = wr * 64 + mi * 16 + (lane >> 4) * 4 + q;
        P[(size_t)(gr0 + rowl) * DDIM + ct * 128 + coll] = acc[mi][ni][q];
      }
  }
}

// ---------- 6: combine: out[tok] = g0*(P0+P1)[row0] + g1*(P0+P1)[row1] ----------
__global__ void combine_kernel(const float* __restrict__ P0, const float* __restrict__ P1,
                               const int4* __restrict__ rec_i, const float2* __restrict__ rec_g,
                               const int* __restrict__ pofs, float* __restrict__ out) {
  int tok = blockIdx.x;
  int c = threadIdx.x * 4;
  int4 ri = rec_i[tok];
  float2 rg = rec_g[tok];
  size_t r0 = (size_t)(pofs[ri.x] + ri.y) * DDIM + c;
  size_t r1 = (size_t)(pofs[ri.z] + ri.w) * DDIM + c;
  float4 a0 = *(const float4*)(P0 + r0);
  float4 b0 = *(const float4*)(P1 + r0);
  float4 a1 = *(const float4*)(P0 + r1);
  float4 b1 = *(const float4*)(P1 + r1);
  float4 o;
  o.x = rg.x * (a0.x + b0.x) + rg.y * (a1.x + b1.x);
  o.y = rg.x * (a0.y + b0.y) + rg.y * (a1.y + b1.y);
  o.z = rg.x * (a0.z + b0.z) + rg.y * (a1.z + b1.z);
  o.w = rg.x * (a0.w + b0.w) + rg.y * (a1.w + b1.w);
  *(float4*)(out + (size_t)tok * DDIM + c) = o;
}

// ---------- launch ----------
extern "C" void kernel_launch(void* const* d_in, const int* in_sizes, int n_in,
                              void* d_out, int out_size, void* d_ws, size_t ws_size,
                              hipStream_t stream) {
  const float* x  = (const float*)d_in[0];
  const float* rw = (const float*)d_in[1];
  const float* wv = (const float*)d_in[2];
  const float* sv = (const float*)d_in[3];
  const float* w  = (const float*)d_in[4];
  const float* s  = (const float*)d_in[5];
  const float* w1 = (const float*)d_in[6];
  const float* s1 = (const float*)d_in[7];
  float* out = (float*)d_out;

  char* ws = (char*)d_ws;
  int*    cnt      = (int*)(ws + 0);
  int*    pofs     = (int*)(ws + 64);
  int*    meta     = (int*)(ws + 128);
  int*    tle      = (int*)(ws + 192);
  int*    tlr      = (int*)(ws + 1024);
  int*    tmp_tok  = (int*)(ws + 2048);
  int*    ptok     = (int*)(ws + 133120);
  int4*   rec_i    = (int4*)(ws + 174080);
  float2* rec_g    = (float2*)(ws + 206848);
  ushort_t* Xg     = (ushort_t*)(ws + 223232);       // 10 MB
  ushort_t* G      = (ushort_t*)(ws + 10708992);     // 40 MB
  ushort_t* WvT    = (ushort_t*)(ws + 52652032);     // 64 MB (dead after gemm1)
  ushort_t* WT     = (ushort_t*)(ws + 119760896);    // 64 MB
  ushort_t* W1T    = (ushort_t*)(ws + 186869760);    // 64 MB (end ~242 MB)
  float*  P0       = (float*)(ws + 52652032);        // overlay old WvT (20 MB)
  float*  P1       = (float*)(ws + 73623552);        // overlay old WvT (20 MB)

  hipMemsetAsync(cnt, 0, NEXP * sizeof(int), stream);
  conv_router_kernel<<<12800, 256, 0, stream>>>(wv, sv, w, s, w1, s1, WvT, WT, W1T,
                                                x, rw, cnt, tmp_tok, rec_i, rec_g);
  finalize_kernel<<<1, 256, 0, stream>>>(cnt, pofs, meta, tle, tlr, ptok, tmp_tok);
  gather_kernel<<<5120, 256, 0, stream>>>(x, ptok, meta, Xg);
  gemm1_kernel<<<1280, 256, 0, stream>>>(Xg, WvT, WT, tle, tlr, meta, G);
  gemm2_kernel<<<640, 256, 0, stream>>>(G, W1T, tle, tlr, meta, P0, P1);
  combine_kernel<<<2048, 256, 0, stream>>>(P0, P1, rec_i, rec_g, pofs, out);
}